// Round 1
// baseline (8608.507 us; speedup 1.0000x reference)
//
#include <hip/hip_runtime.h>
#include <hip/hip_bf16.h>

#define N_SRC0 400000
#define N_DST0 100000
#define N_DST1 25000

// ---------------- degree histogram ----------------
__global__ void deg_kernel(const int* __restrict__ idx, float* __restrict__ deg, int n) {
    int i = blockIdx.x * blockDim.x + threadIdx.x;
    if (i < n) atomicAdd(&deg[idx[i]], 1.0f);
}

// ---------------- layer-0 scatter: agg[dst] += x[src] * cs[src], 128 feats ----------------
// 32 threads per edge, float4 each
__global__ void scatter0_kernel(const float* __restrict__ x,
                                const int* __restrict__ src, const int* __restrict__ dst,
                                const float* __restrict__ degout,
                                float* __restrict__ agg, int nE) {
    long long gid = (long long)blockIdx.x * blockDim.x + threadIdx.x;
    long long total = (long long)nE * 32;
    if (gid >= total) return;
    int e  = (int)(gid >> 5);
    int k4 = (int)(gid & 31);
    int s = src[e];
    int d = dst[e];
    float cs = rsqrtf(degout[s]);   // s appears in src => deg >= 1
    float4 v = *(const float4*)(x + (long long)s * 128 + k4 * 4);
    float* o = agg + (long long)d * 128 + k4 * 4;
    atomicAdd(o + 0, v.x * cs);
    atomicAdd(o + 1, v.y * cs);
    atomicAdd(o + 2, v.z * cs);
    atomicAdd(o + 3, v.w * cs);
}

// ---------------- layer-1 scatter: 256 feats, 64 threads per edge ----------------
__global__ void scatter1_kernel(const float* __restrict__ h,
                                const int* __restrict__ src, const int* __restrict__ dst,
                                const float* __restrict__ degout,
                                float* __restrict__ agg, int nE) {
    long long gid = (long long)blockIdx.x * blockDim.x + threadIdx.x;
    long long total = (long long)nE * 64;
    if (gid >= total) return;
    int e  = (int)(gid >> 6);
    int k4 = (int)(gid & 63);
    int s = src[e];
    int d = dst[e];
    float cs = rsqrtf(degout[s]);
    float4 v = *(const float4*)(h + (long long)s * 256 + k4 * 4);
    float* o = agg + (long long)d * 256 + k4 * 4;
    atomicAdd(o + 0, v.x * cs);
    atomicAdd(o + 1, v.y * cs);
    atomicAdd(o + 2, v.z * cs);
    atomicAdd(o + 3, v.w * cs);
}

// ---------------- GEMM0: [100000,128] x [128,256], row-scale cd, +bias, relu ----------------
// block = 256 threads (one per output column), 16 rows per block; nrows % 16 == 0
__global__ __launch_bounds__(256) void gemm0_kernel(
        const float* __restrict__ agg, const float* __restrict__ degin,
        const float* __restrict__ W, const float* __restrict__ bias,
        float* __restrict__ out, int nrows) {
    __shared__ float As[16][128];
    const int tid = threadIdx.x;
    const int rowBase = blockIdx.x * 16;

    // load + scale A tile: 16x128 floats = 512 float4, 2 per thread
    #pragma unroll
    for (int i = 0; i < 2; ++i) {
        int f4 = tid + i * 256;
        int r  = f4 >> 5;      // 32 float4 per row
        int k4 = f4 & 31;
        int row = rowBase + r;
        float dg = degin[row];
        float cd = dg > 0.f ? rsqrtf(dg) : 0.f;
        float4 v = *(const float4*)(agg + (long long)row * 128 + k4 * 4);
        v.x *= cd; v.y *= cd; v.z *= cd; v.w *= cd;
        *(float4*)(&As[r][k4 * 4]) = v;
    }
    __syncthreads();

    const int c = tid;
    float bv = bias[c];
    float acc[16];
    #pragma unroll
    for (int r = 0; r < 16; ++r) acc[r] = bv;

    for (int k4 = 0; k4 < 32; ++k4) {
        float w0 = W[(k4 * 4 + 0) * 256 + c];
        float w1 = W[(k4 * 4 + 1) * 256 + c];
        float w2 = W[(k4 * 4 + 2) * 256 + c];
        float w3 = W[(k4 * 4 + 3) * 256 + c];
        #pragma unroll
        for (int r = 0; r < 16; ++r) {
            float4 a = *(const float4*)(&As[r][k4 * 4]);
            acc[r] = fmaf(a.x, w0, acc[r]);
            acc[r] = fmaf(a.y, w1, acc[r]);
            acc[r] = fmaf(a.z, w2, acc[r]);
            acc[r] = fmaf(a.w, w3, acc[r]);
        }
    }
    #pragma unroll
    for (int r = 0; r < 16; ++r) {
        out[(long long)(rowBase + r) * 256 + c] = fmaxf(acc[r], 0.f);
    }
}

// ---------------- GEMM1: [25000,256] x [256,64], row-scale cd, +bias, relu ----------------
// block = 256 threads = 4 row-subgroups x 64 cols; 32 rows per block
__global__ __launch_bounds__(256) void gemm1_kernel(
        const float* __restrict__ agg, const float* __restrict__ degin,
        const float* __restrict__ W, const float* __restrict__ bias,
        float* __restrict__ out, int nrows) {
    __shared__ float As[32][256];   // 32 KB
    const int tid = threadIdx.x;
    const int rowBase = blockIdx.x * 32;

    // load + scale A tile: 32x256 floats = 2048 float4, 8 per thread
    #pragma unroll
    for (int i = 0; i < 8; ++i) {
        int f4 = tid + i * 256;
        int r  = f4 >> 6;      // 64 float4 per row
        int k4 = f4 & 63;
        int row = rowBase + r;
        float4 v = make_float4(0.f, 0.f, 0.f, 0.f);
        if (row < nrows) {
            float dg = degin[row];
            float cd = dg > 0.f ? rsqrtf(dg) : 0.f;
            v = *(const float4*)(agg + (long long)row * 256 + k4 * 4);
            v.x *= cd; v.y *= cd; v.z *= cd; v.w *= cd;
        }
        *(float4*)(&As[r][k4 * 4]) = v;
    }
    __syncthreads();

    const int c  = tid & 63;
    const int rq = tid >> 6;   // 0..3, each handles 8 rows
    float bv = bias[c];
    float acc[8];
    #pragma unroll
    for (int r = 0; r < 8; ++r) acc[r] = bv;

    for (int k4 = 0; k4 < 64; ++k4) {
        float w0 = W[(k4 * 4 + 0) * 64 + c];
        float w1 = W[(k4 * 4 + 1) * 64 + c];
        float w2 = W[(k4 * 4 + 2) * 64 + c];
        float w3 = W[(k4 * 4 + 3) * 64 + c];
        #pragma unroll
        for (int r = 0; r < 8; ++r) {
            float4 a = *(const float4*)(&As[rq * 8 + r][k4 * 4]);
            acc[r] = fmaf(a.x, w0, acc[r]);
            acc[r] = fmaf(a.y, w1, acc[r]);
            acc[r] = fmaf(a.z, w2, acc[r]);
            acc[r] = fmaf(a.w, w3, acc[r]);
        }
    }
    #pragma unroll
    for (int r = 0; r < 8; ++r) {
        int row = rowBase + rq * 8 + r;
        if (row < nrows) out[(long long)row * 64 + c] = fmaxf(acc[r], 0.f);
    }
}

extern "C" void kernel_launch(void* const* d_in, const int* in_sizes, int n_in,
                              void* d_out, int out_size, void* d_ws, size_t ws_size,
                              hipStream_t stream) {
    const float* x    = (const float*)d_in[0];
    const int*   src0 = (const int*)d_in[1];
    const int*   dst0 = (const int*)d_in[2];
    const int*   src1 = (const int*)d_in[3];
    const int*   dst1 = (const int*)d_in[4];
    const float* W0   = (const float*)d_in[5];
    const float* b0   = (const float*)d_in[6];
    const float* W1   = (const float*)d_in[7];
    const float* b1   = (const float*)d_in[8];
    float* out = (float*)d_out;

    const int E0 = in_sizes[1];
    const int E1 = in_sizes[3];

    // workspace layout (512B aligned)
    char* p = (char*)d_ws;
    auto alloc = [&](size_t bytes) {
        char* r = p;
        p += (bytes + 511) & ~(size_t)511;
        return r;
    };
    float* degout0 = (float*)alloc((size_t)N_SRC0 * 4);
    float* degin0  = (float*)alloc((size_t)N_DST0 * 4);
    float* degout1 = (float*)alloc((size_t)N_DST0 * 4);
    float* degin1  = (float*)alloc((size_t)N_DST1 * 4);
    float* agg0    = (float*)alloc((size_t)N_DST0 * 128 * 4);
    float* h0      = (float*)alloc((size_t)N_DST0 * 256 * 4);
    float* agg1    = (float*)alloc((size_t)N_DST1 * 256 * 4);

    // zero accumulators (must be re-zeroed every call: graph replays reuse ws)
    hipMemsetAsync(degout0, 0, (size_t)N_SRC0 * 4, stream);
    hipMemsetAsync(degin0,  0, (size_t)N_DST0 * 4, stream);
    hipMemsetAsync(degout1, 0, (size_t)N_DST0 * 4, stream);
    hipMemsetAsync(degin1,  0, (size_t)N_DST1 * 4, stream);
    hipMemsetAsync(agg0, 0, (size_t)N_DST0 * 128 * 4, stream);
    hipMemsetAsync(agg1, 0, (size_t)N_DST1 * 256 * 4, stream);

    // degrees
    {
        int blocks = (E0 + 255) / 256;
        deg_kernel<<<blocks, 256, 0, stream>>>(src0, degout0, E0);
        deg_kernel<<<blocks, 256, 0, stream>>>(dst0, degin0, E0);
        blocks = (E1 + 255) / 256;
        deg_kernel<<<blocks, 256, 0, stream>>>(src1, degout1, E1);
        deg_kernel<<<blocks, 256, 0, stream>>>(dst1, degin1, E1);
    }

    // layer 0: scatter + gemm
    {
        long long total = (long long)E0 * 32;
        int blocks = (int)((total + 255) / 256);
        scatter0_kernel<<<blocks, 256, 0, stream>>>(x, src0, dst0, degout0, agg0, E0);
        gemm0_kernel<<<N_DST0 / 16, 256, 0, stream>>>(agg0, degin0, W0, b0, h0, N_DST0);
    }

    // layer 1: scatter + gemm
    {
        long long total = (long long)E1 * 64;
        int blocks = (int)((total + 255) / 256);
        scatter1_kernel<<<blocks, 256, 0, stream>>>(h0, src1, dst1, degout1, agg1, E1);
        gemm1_kernel<<<(N_DST1 + 31) / 32, 256, 0, stream>>>(agg1, degin1, W1, b1, out, N_DST1);
    }
}

// Round 2
// 1333.970 us; speedup vs baseline: 6.4533x; 6.4533x over previous
//
#include <hip/hip_runtime.h>
#include <hip/hip_bf16.h>

#define N_SRC0 400000
#define N_DST0 100000
#define N_DST1 25000

// ---------------- degree histograms (int) ----------------
__global__ void count2_kernel(const int* __restrict__ src, const int* __restrict__ dst,
                              int* __restrict__ odeg, int* __restrict__ cnt, int n) {
    int i = blockIdx.x * blockDim.x + threadIdx.x;
    if (i < n) {
        atomicAdd(&odeg[src[i]], 1);
        atomicAdd(&cnt[dst[i]], 1);
    }
}

// cs[i] = cnt>0 ? rsqrt(cnt) : 0
__global__ void rsqrt_kernel(const int* __restrict__ cnt, float* __restrict__ cs, int n) {
    int i = blockIdx.x * blockDim.x + threadIdx.x;
    if (i < n) {
        int c = cnt[i];
        cs[i] = c > 0 ? rsqrtf((float)c) : 0.f;
    }
}

// ---------------- two-level exclusive scan ----------------
#define SCAN_BLOCK 256
#define SCAN_ITEMS 4
#define SCAN_TILE (SCAN_BLOCK * SCAN_ITEMS)

__global__ __launch_bounds__(SCAN_BLOCK) void scan1_kernel(
        const int* __restrict__ in, int* __restrict__ out,
        int* __restrict__ sums, int n) {
    __shared__ int lds[SCAN_BLOCK];
    const int tid = threadIdx.x;
    const int base = blockIdx.x * SCAN_TILE + tid * SCAN_ITEMS;
    int v[SCAN_ITEMS];
    int run = 0;
    #pragma unroll
    for (int i = 0; i < SCAN_ITEMS; ++i) {
        int t = (base + i < n) ? in[base + i] : 0;
        v[i] = run;
        run += t;
    }
    lds[tid] = run;
    __syncthreads();
    int incl = run;
    for (int off = 1; off < SCAN_BLOCK; off <<= 1) {
        int u = (tid >= off) ? lds[tid - off] : 0;
        __syncthreads();
        incl += u;
        lds[tid] = incl;
        __syncthreads();
    }
    if (tid == SCAN_BLOCK - 1) sums[blockIdx.x] = incl;  // block total
    int excl = incl - run;
    #pragma unroll
    for (int i = 0; i < SCAN_ITEMS; ++i)
        if (base + i < n) out[base + i] = excl + v[i];
}

// single-block exclusive scan of block sums (nb <= 128)
__global__ __launch_bounds__(128) void scan2_kernel(int* __restrict__ sums, int nb) {
    __shared__ int lds[128];
    const int tid = threadIdx.x;
    int v = (tid < nb) ? sums[tid] : 0;
    lds[tid] = v;
    __syncthreads();
    int incl = v;
    for (int off = 1; off < 128; off <<= 1) {
        int u = (tid >= off) ? lds[tid - off] : 0;
        __syncthreads();
        incl += u;
        lds[tid] = incl;
        __syncthreads();
    }
    if (tid < nb) sums[tid] = incl - v;  // exclusive
}

__global__ void scan3_kernel(int* __restrict__ out, const int* __restrict__ sums,
                             int n, int total) {
    int i = blockIdx.x * blockDim.x + threadIdx.x;
    if (i < n) out[i] += sums[i / SCAN_TILE];
    if (i == 0) out[n] = total;
}

// ---------------- CSR bucket fill ----------------
__global__ void fill_kernel(const int* __restrict__ src, const int* __restrict__ dst,
                            const int* __restrict__ off, int* __restrict__ cur,
                            int* __restrict__ esrc, int n) {
    int i = blockIdx.x * blockDim.x + threadIdx.x;
    if (i < n) {
        int d = dst[i];
        int p = off[d] + atomicAdd(&cur[d], 1);
        esrc[p] = src[i];
    }
}

// ---------------- layer-0 aggregation: 128 threads per dst row ----------------
__global__ __launch_bounds__(256) void agg0_kernel(
        const float* __restrict__ x, const int* __restrict__ esrc,
        const int* __restrict__ off, const float* __restrict__ cs,
        float* __restrict__ agg, int nrows) {
    int row = blockIdx.x * 2 + (threadIdx.x >> 7);
    int t = threadIdx.x & 127;
    if (row >= nrows) return;
    int b = off[row], e = off[row + 1];
    float acc = 0.f;
    int i = b;
    for (; i + 1 < e; i += 2) {
        int s0 = esrc[i], s1 = esrc[i + 1];
        float c0 = cs[s0], c1 = cs[s1];
        float f0 = x[(size_t)s0 * 128 + t];
        float f1 = x[(size_t)s1 * 128 + t];
        acc = fmaf(f0, c0, acc);
        acc = fmaf(f1, c1, acc);
    }
    if (i < e) {
        int s = esrc[i];
        acc = fmaf(x[(size_t)s * 128 + t], cs[s], acc);
    }
    float cd = (e > b) ? rsqrtf((float)(e - b)) : 0.f;
    agg[(size_t)row * 128 + t] = acc * cd;
}

// ---------------- layer-1 aggregation (64-wide, post-transform) + bias + relu ----
__global__ __launch_bounds__(256) void agg1_kernel(
        const float* __restrict__ y, const int* __restrict__ esrc,
        const int* __restrict__ off, const float* __restrict__ cs,
        const float* __restrict__ bias, float* __restrict__ out, int nrows) {
    int row = blockIdx.x * 4 + (threadIdx.x >> 6);
    int t = threadIdx.x & 63;
    if (row >= nrows) return;
    int b = off[row], e = off[row + 1];
    float acc = 0.f;
    int i = b;
    for (; i + 1 < e; i += 2) {
        int s0 = esrc[i], s1 = esrc[i + 1];
        float c0 = cs[s0], c1 = cs[s1];
        float f0 = y[(size_t)s0 * 64 + t];
        float f1 = y[(size_t)s1 * 64 + t];
        acc = fmaf(f0, c0, acc);
        acc = fmaf(f1, c1, acc);
    }
    if (i < e) {
        int s = esrc[i];
        acc = fmaf(y[(size_t)s * 64 + t], cs[s], acc);
    }
    float cd = (e > b) ? rsqrtf((float)(e - b)) : 0.f;
    out[(size_t)row * 64 + t] = fmaxf(acc * cd + bias[t], 0.f);
}

// ---------------- GEMM0: [N_DST0,128] x [128,256], +bias, relu ----------------
// block = 256 threads (one per output column), 16 rows per block; nrows % 16 == 0
__global__ __launch_bounds__(256) void gemm0_kernel(
        const float* __restrict__ agg, const float* __restrict__ W,
        const float* __restrict__ bias, float* __restrict__ out, int nrows) {
    __shared__ float As[16][128];
    const int tid = threadIdx.x;
    const int rowBase = blockIdx.x * 16;

    #pragma unroll
    for (int i = 0; i < 2; ++i) {
        int f4 = tid + i * 256;
        int r = f4 >> 5;
        int k4 = f4 & 31;
        float4 v = *(const float4*)(agg + (size_t)(rowBase + r) * 128 + k4 * 4);
        *(float4*)(&As[r][k4 * 4]) = v;
    }
    __syncthreads();

    const int c = tid;
    float bv = bias[c];
    float acc[16];
    #pragma unroll
    for (int r = 0; r < 16; ++r) acc[r] = bv;

    for (int k4 = 0; k4 < 32; ++k4) {
        float w0 = W[(k4 * 4 + 0) * 256 + c];
        float w1 = W[(k4 * 4 + 1) * 256 + c];
        float w2 = W[(k4 * 4 + 2) * 256 + c];
        float w3 = W[(k4 * 4 + 3) * 256 + c];
        #pragma unroll
        for (int r = 0; r < 16; ++r) {
            float4 a = *(const float4*)(&As[r][k4 * 4]);
            acc[r] = fmaf(a.x, w0, acc[r]);
            acc[r] = fmaf(a.y, w1, acc[r]);
            acc[r] = fmaf(a.z, w2, acc[r]);
            acc[r] = fmaf(a.w, w3, acc[r]);
        }
    }
    #pragma unroll
    for (int r = 0; r < 16; ++r) {
        out[(size_t)(rowBase + r) * 256 + c] = fmaxf(acc[r], 0.f);
    }
}

// ---------------- GEMM-T: y = h0 @ W1, [N_DST0,256] x [256,64], no epilogue ----
// block = 256 = 4 row-groups x 64 cols; 32 rows per block; nrows % 32 == 0
__global__ __launch_bounds__(256) void gemmt_kernel(
        const float* __restrict__ A, const float* __restrict__ W,
        float* __restrict__ Y) {
    __shared__ float As[32][256];  // 32 KB
    const int tid = threadIdx.x;
    const int rowBase = blockIdx.x * 32;

    #pragma unroll
    for (int i = 0; i < 8; ++i) {
        int f4 = tid + i * 256;
        int r = f4 >> 6;
        int k4 = f4 & 63;
        float4 v = *(const float4*)(A + (size_t)(rowBase + r) * 256 + k4 * 4);
        *(float4*)(&As[r][k4 * 4]) = v;
    }
    __syncthreads();

    const int c = tid & 63;
    const int rq = tid >> 6;
    float acc[8];
    #pragma unroll
    for (int r = 0; r < 8; ++r) acc[r] = 0.f;

    for (int k4 = 0; k4 < 64; ++k4) {
        float w0 = W[(k4 * 4 + 0) * 64 + c];
        float w1 = W[(k4 * 4 + 1) * 64 + c];
        float w2 = W[(k4 * 4 + 2) * 64 + c];
        float w3 = W[(k4 * 4 + 3) * 64 + c];
        #pragma unroll
        for (int r = 0; r < 8; ++r) {
            float4 a = *(const float4*)(&As[rq * 8 + r][k4 * 4]);
            acc[r] = fmaf(a.x, w0, acc[r]);
            acc[r] = fmaf(a.y, w1, acc[r]);
            acc[r] = fmaf(a.z, w2, acc[r]);
            acc[r] = fmaf(a.w, w3, acc[r]);
        }
    }
    #pragma unroll
    for (int r = 0; r < 8; ++r) {
        Y[(size_t)(rowBase + rq * 8 + r) * 64 + c] = acc[r];
    }
}

extern "C" void kernel_launch(void* const* d_in, const int* in_sizes, int n_in,
                              void* d_out, int out_size, void* d_ws, size_t ws_size,
                              hipStream_t stream) {
    const float* x    = (const float*)d_in[0];
    const int*   src0 = (const int*)d_in[1];
    const int*   dst0 = (const int*)d_in[2];
    const int*   src1 = (const int*)d_in[3];
    const int*   dst1 = (const int*)d_in[4];
    const float* W0   = (const float*)d_in[5];
    const float* b0   = (const float*)d_in[6];
    const float* W1   = (const float*)d_in[7];
    const float* b1   = (const float*)d_in[8];
    float* out = (float*)d_out;

    const int E0 = in_sizes[1];
    const int E1 = in_sizes[3];

    // workspace layout
    char* p = (char*)d_ws;
    auto alloc = [&](size_t bytes) {
        char* r = p;
        p += (bytes + 511) & ~(size_t)511;
        return r;
    };
    int*   odeg0 = (int*)alloc((size_t)N_SRC0 * 4);
    float* cs0   = (float*)alloc((size_t)N_SRC0 * 4);
    int*   cnt0  = (int*)alloc((size_t)N_DST0 * 4);
    int*   cur0  = (int*)alloc((size_t)N_DST0 * 4);
    int*   off0  = (int*)alloc((size_t)(N_DST0 + 1) * 4);
    int*   sums0 = (int*)alloc(128 * 4);
    int*   odeg1 = (int*)alloc((size_t)N_DST0 * 4);
    float* cs1   = (float*)alloc((size_t)N_DST0 * 4);
    int*   cnt1  = (int*)alloc((size_t)N_DST1 * 4);
    int*   cur1  = (int*)alloc((size_t)N_DST1 * 4);
    int*   off1  = (int*)alloc((size_t)(N_DST1 + 1) * 4);
    int*   sums1 = (int*)alloc(128 * 4);
    int*   esrc0 = (int*)alloc((size_t)E0 * 4);
    int*   esrc1 = (int*)alloc((size_t)E1 * 4);
    float* aggbuf = (float*)alloc((size_t)N_DST0 * 128 * 4);  // also reused as y1
    float* h0    = (float*)alloc((size_t)N_DST0 * 256 * 4);
    float* y1    = aggbuf;  // alias: agg0 dead after gemm0

    // zero counters (graph replays reuse ws)
    hipMemsetAsync(odeg0, 0, (size_t)N_SRC0 * 4, stream);
    hipMemsetAsync(cnt0,  0, (size_t)N_DST0 * 4, stream);
    hipMemsetAsync(cur0,  0, (size_t)N_DST0 * 4, stream);
    hipMemsetAsync(odeg1, 0, (size_t)N_DST0 * 4, stream);
    hipMemsetAsync(cnt1,  0, (size_t)N_DST1 * 4, stream);
    hipMemsetAsync(cur1,  0, (size_t)N_DST1 * 4, stream);

    // degrees
    count2_kernel<<<(E0 + 255) / 256, 256, 0, stream>>>(src0, dst0, odeg0, cnt0, E0);
    count2_kernel<<<(E1 + 255) / 256, 256, 0, stream>>>(src1, dst1, odeg1, cnt1, E1);
    rsqrt_kernel<<<(N_SRC0 + 255) / 256, 256, 0, stream>>>(odeg0, cs0, N_SRC0);
    rsqrt_kernel<<<(N_DST0 + 255) / 256, 256, 0, stream>>>(odeg1, cs1, N_DST0);

    // CSR offsets
    const int nb0 = (N_DST0 + SCAN_TILE - 1) / SCAN_TILE;
    const int nb1 = (N_DST1 + SCAN_TILE - 1) / SCAN_TILE;
    scan1_kernel<<<nb0, SCAN_BLOCK, 0, stream>>>(cnt0, off0, sums0, N_DST0);
    scan2_kernel<<<1, 128, 0, stream>>>(sums0, nb0);
    scan3_kernel<<<(N_DST0 + 255) / 256, 256, 0, stream>>>(off0, sums0, N_DST0, E0);
    scan1_kernel<<<nb1, SCAN_BLOCK, 0, stream>>>(cnt1, off1, sums1, N_DST1);
    scan2_kernel<<<1, 128, 0, stream>>>(sums1, nb1);
    scan3_kernel<<<(N_DST1 + 255) / 256, 256, 0, stream>>>(off1, sums1, N_DST1, E1);

    // bucket fill
    fill_kernel<<<(E0 + 255) / 256, 256, 0, stream>>>(src0, dst0, off0, cur0, esrc0, E0);
    fill_kernel<<<(E1 + 255) / 256, 256, 0, stream>>>(src1, dst1, off1, cur1, esrc1, E1);

    // layer 0: gather-aggregate + GEMM(+bias,relu)
    agg0_kernel<<<(N_DST0 + 1) / 2, 256, 0, stream>>>(x, esrc0, off0, cs0, aggbuf, N_DST0);
    gemm0_kernel<<<N_DST0 / 16, 256, 0, stream>>>(aggbuf, W0, b0, h0, N_DST0);

    // layer 1: transform-first GEMM, then gather-aggregate(+bias,relu)
    gemmt_kernel<<<N_DST0 / 32, 256, 0, stream>>>(h0, W1, y1);
    agg1_kernel<<<(N_DST1 + 3) / 4, 256, 0, stream>>>(y1, esrc1, off1, cs1, b1, out, N_DST1);
}

// Round 3
// 819.251 us; speedup vs baseline: 10.5078x; 1.6283x over previous
//
#include <hip/hip_runtime.h>
#include <hip/hip_bf16.h>
#include <stdint.h>

#define N_SRC0 400000
#define N_DST0 100000
#define N_DST1 25000

typedef __attribute__((ext_vector_type(8))) short short8;
typedef __attribute__((ext_vector_type(4))) float f32x4;

__device__ __forceinline__ unsigned short f2bf(float f) {
    __hip_bfloat16 h = __float2bfloat16(f);
    union { __hip_bfloat16 h; unsigned short u; } c;
    c.h = h;
    return c.u;
}
__device__ __forceinline__ float bfu_lo(uint32_t u) { return __uint_as_float(u << 16); }
__device__ __forceinline__ float bfu_hi(uint32_t u) { return __uint_as_float(u & 0xffff0000u); }
__device__ __forceinline__ uint32_t packbf2(float a, float b) {
    return (uint32_t)f2bf(a) | ((uint32_t)f2bf(b) << 16);
}

// ---------------- degree histograms (int) ----------------
__global__ void count2_kernel(const int* __restrict__ src, const int* __restrict__ dst,
                              int* __restrict__ odeg, int* __restrict__ cnt, int n) {
    int i = blockIdx.x * blockDim.x + threadIdx.x;
    if (i < n) {
        atomicAdd(&odeg[src[i]], 1);
        atomicAdd(&cnt[dst[i]], 1);
    }
}

__global__ void rsqrt_kernel(const int* __restrict__ cnt, float* __restrict__ cs, int n) {
    int i = blockIdx.x * blockDim.x + threadIdx.x;
    if (i < n) {
        int c = cnt[i];
        cs[i] = c > 0 ? rsqrtf((float)c) : 0.f;
    }
}

// ---------------- two-level exclusive scan ----------------
#define SCAN_BLOCK 256
#define SCAN_ITEMS 4
#define SCAN_TILE (SCAN_BLOCK * SCAN_ITEMS)

__global__ __launch_bounds__(SCAN_BLOCK) void scan1_kernel(
        const int* __restrict__ in, int* __restrict__ out,
        int* __restrict__ sums, int n) {
    __shared__ int lds[SCAN_BLOCK];
    const int tid = threadIdx.x;
    const int base = blockIdx.x * SCAN_TILE + tid * SCAN_ITEMS;
    int v[SCAN_ITEMS];
    int run = 0;
    #pragma unroll
    for (int i = 0; i < SCAN_ITEMS; ++i) {
        int t = (base + i < n) ? in[base + i] : 0;
        v[i] = run;
        run += t;
    }
    lds[tid] = run;
    __syncthreads();
    int incl = run;
    for (int off = 1; off < SCAN_BLOCK; off <<= 1) {
        int u = (tid >= off) ? lds[tid - off] : 0;
        __syncthreads();
        incl += u;
        lds[tid] = incl;
        __syncthreads();
    }
    if (tid == SCAN_BLOCK - 1) sums[blockIdx.x] = incl;
    int excl = incl - run;
    #pragma unroll
    for (int i = 0; i < SCAN_ITEMS; ++i)
        if (base + i < n) out[base + i] = excl + v[i];
}

__global__ __launch_bounds__(128) void scan2_kernel(int* __restrict__ sums, int nb) {
    __shared__ int lds[128];
    const int tid = threadIdx.x;
    int v = (tid < nb) ? sums[tid] : 0;
    lds[tid] = v;
    __syncthreads();
    int incl = v;
    for (int off = 1; off < 128; off <<= 1) {
        int u = (tid >= off) ? lds[tid - off] : 0;
        __syncthreads();
        incl += u;
        lds[tid] = incl;
        __syncthreads();
    }
    if (tid < nb) sums[tid] = incl - v;
}

__global__ void scan3_kernel(int* __restrict__ out, const int* __restrict__ sums,
                             int n, int total) {
    int i = blockIdx.x * blockDim.x + threadIdx.x;
    if (i < n) out[i] += sums[i / SCAN_TILE];
    if (i == 0) out[n] = total;
}

// ---------------- CSR bucket fill ----------------
__global__ void fill_kernel(const int* __restrict__ src, const int* __restrict__ dst,
                            const int* __restrict__ off, int* __restrict__ cur,
                            int* __restrict__ esrc, int n) {
    int i = blockIdx.x * blockDim.x + threadIdx.x;
    if (i < n) {
        int d = dst[i];
        int p = off[d] + atomicAdd(&cur[d], 1);
        esrc[p] = src[i];
    }
}

// ---------------- prescale: xs = bf16(x * cs0), [N_SRC0,128] ----------------
// one float4 per thread, exact grid
__global__ __launch_bounds__(256) void prescale_kernel(
        const float4* __restrict__ x4, const float* __restrict__ cs,
        uint2* __restrict__ xs) {
    int id = blockIdx.x * 256 + threadIdx.x;
    int row = id >> 5;
    float c = cs[row];
    float4 v = x4[id];
    uint2 o;
    o.x = packbf2(v.x * c, v.y * c);
    o.y = packbf2(v.z * c, v.w * c);
    xs[id] = o;
}

// ---------------- weight pack: Bp[kt][n][kk] = bf16(W[kt*32+kk][n]) ----------
__global__ void packW0_kernel(const float* __restrict__ W, unsigned short* __restrict__ Bp) {
    int id = blockIdx.x * 256 + threadIdx.x;       // 4*256*32 = 32768
    int kk = id & 31, n = (id >> 5) & 255, kt = id >> 13;
    Bp[id] = f2bf(W[(kt * 32 + kk) * 256 + n]);
}
__global__ void packW1_kernel(const float* __restrict__ W, unsigned short* __restrict__ Bp) {
    int id = blockIdx.x * 256 + threadIdx.x;       // 8*64*32 = 16384
    int kk = id & 31, n = (id >> 5) & 63, kt = id >> 11;
    Bp[id] = f2bf(W[(kt * 32 + kk) * 64 + n]);
}

// ---------------- layer-0 aggregation: 64 threads/row, bf16 gather ----------
__global__ __launch_bounds__(256) void agg0_kernel(
        const uint32_t* __restrict__ xs, const int* __restrict__ esrc,
        const int* __restrict__ off, uint32_t* __restrict__ aggb, int nrows) {
    int row = blockIdx.x * 4 + (threadIdx.x >> 6);
    int t = threadIdx.x & 63;
    if (row >= nrows) return;
    int b = off[row], e = off[row + 1];
    float a0 = 0.f, a1 = 0.f;
    int i = b;
    for (; i + 3 < e; i += 4) {
        int s0 = esrc[i], s1 = esrc[i + 1], s2 = esrc[i + 2], s3 = esrc[i + 3];
        uint32_t u0 = xs[(size_t)s0 * 64 + t];
        uint32_t u1 = xs[(size_t)s1 * 64 + t];
        uint32_t u2 = xs[(size_t)s2 * 64 + t];
        uint32_t u3 = xs[(size_t)s3 * 64 + t];
        a0 += (bfu_lo(u0) + bfu_lo(u1)) + (bfu_lo(u2) + bfu_lo(u3));
        a1 += (bfu_hi(u0) + bfu_hi(u1)) + (bfu_hi(u2) + bfu_hi(u3));
    }
    for (; i < e; ++i) {
        uint32_t u = xs[(size_t)esrc[i] * 64 + t];
        a0 += bfu_lo(u);
        a1 += bfu_hi(u);
    }
    float cd = (e > b) ? rsqrtf((float)(e - b)) : 0.f;
    aggb[(size_t)row * 64 + t] = packbf2(a0 * cd, a1 * cd);
}

// ---------------- GEMM0 (MFMA): h = relu(agg @ W0 + b0), bf16 out ----------
// block = 4 waves; wave w: rows [blk*32, +32), cols [w*64, +64); K = 128
__global__ __launch_bounds__(256) void gemm0_mfma(
        const short* __restrict__ A,            // [N_DST0][128] bf16
        const short* __restrict__ Bp,           // [4][256][32] bf16
        const float* __restrict__ bias,         // [256]
        unsigned short* __restrict__ H) {       // [>=N_DST0][256] bf16
    const int w = threadIdx.x >> 6;
    const int l = threadIdx.x & 63;
    const int rbase = blockIdx.x * 32;
    const int cbase = w * 64;
    const int lr = l & 15;
    const int lk = (l >> 4) * 8;
    f32x4 acc[2][4] = {};
    #pragma unroll
    for (int kt = 0; kt < 4; ++kt) {
        short8 a[2], b[4];
        #pragma unroll
        for (int rt = 0; rt < 2; ++rt)
            a[rt] = *(const short8*)(A + (size_t)(rbase + rt * 16 + lr) * 128 + kt * 32 + lk);
        #pragma unroll
        for (int ct = 0; ct < 4; ++ct)
            b[ct] = *(const short8*)(Bp + (size_t)(kt * 256 + cbase + ct * 16 + lr) * 32 + lk);
        #pragma unroll
        for (int rt = 0; rt < 2; ++rt)
            #pragma unroll
            for (int ct = 0; ct < 4; ++ct)
                acc[rt][ct] = __builtin_amdgcn_mfma_f32_16x16x32_bf16(a[rt], b[ct], acc[rt][ct], 0, 0, 0);
    }
    const int orow0 = (l >> 4) * 4;
    #pragma unroll
    for (int rt = 0; rt < 2; ++rt) {
        #pragma unroll
        for (int ct = 0; ct < 4; ++ct) {
            int col = cbase + ct * 16 + lr;
            float bv = bias[col];
            #pragma unroll
            for (int j = 0; j < 4; ++j) {
                int row = rbase + rt * 16 + orow0 + j;
                float v = fmaxf(acc[rt][ct][j] + bv, 0.f);
                H[(size_t)row * 256 + col] = f2bf(v);
            }
        }
    }
}

// ---------------- GEMM-T (MFMA): y = (h0 @ W1) * cs1[row], bf16 out --------
// block = 4 waves; wave w: rows [blk*128 + w*32, +32), cols [0,64); K = 256
__global__ __launch_bounds__(256) void gemmt_mfma(
        const short* __restrict__ A,            // [M_PAD][256] bf16
        const short* __restrict__ Bp,           // [8][64][32] bf16
        const float* __restrict__ cs1,          // [N_DST0]
        unsigned short* __restrict__ Y,         // [N_DST0][64] bf16
        int M) {
    const int w = threadIdx.x >> 6;
    const int l = threadIdx.x & 63;
    const int rbase = blockIdx.x * 128 + w * 32;
    const int lr = l & 15;
    const int lk = (l >> 4) * 8;
    f32x4 acc[2][4] = {};
    #pragma unroll
    for (int kt = 0; kt < 8; ++kt) {
        short8 a[2], b[4];
        #pragma unroll
        for (int rt = 0; rt < 2; ++rt)
            a[rt] = *(const short8*)(A + (size_t)(rbase + rt * 16 + lr) * 256 + kt * 32 + lk);
        #pragma unroll
        for (int ct = 0; ct < 4; ++ct)
            b[ct] = *(const short8*)(Bp + (size_t)(kt * 64 + ct * 16 + lr) * 32 + lk);
        #pragma unroll
        for (int rt = 0; rt < 2; ++rt)
            #pragma unroll
            for (int ct = 0; ct < 4; ++ct)
                acc[rt][ct] = __builtin_amdgcn_mfma_f32_16x16x32_bf16(a[rt], b[ct], acc[rt][ct], 0, 0, 0);
    }
    const int orow0 = (l >> 4) * 4;
    #pragma unroll
    for (int rt = 0; rt < 2; ++rt) {
        #pragma unroll
        for (int j = 0; j < 4; ++j) {
            int row = rbase + rt * 16 + orow0 + j;
            if (row < M) {
                float c = cs1[row];
                #pragma unroll
                for (int ct = 0; ct < 4; ++ct) {
                    int col = ct * 16 + lr;
                    Y[(size_t)row * 64 + col] = f2bf(acc[rt][ct][j] * c);
                }
            }
        }
    }
}

// ---------------- layer-1 aggregation: 32 threads/row, +bias, relu ---------
__global__ __launch_bounds__(256) void agg1_kernel(
        const uint32_t* __restrict__ y, const int* __restrict__ esrc,
        const int* __restrict__ off, const float* __restrict__ bias,
        float* __restrict__ out, int nrows) {
    int row = blockIdx.x * 8 + (threadIdx.x >> 5);
    int t = threadIdx.x & 31;
    if (row >= nrows) return;
    int b = off[row], e = off[row + 1];
    float a0 = 0.f, a1 = 0.f;
    int i = b;
    for (; i + 3 < e; i += 4) {
        int s0 = esrc[i], s1 = esrc[i + 1], s2 = esrc[i + 2], s3 = esrc[i + 3];
        uint32_t u0 = y[(size_t)s0 * 32 + t];
        uint32_t u1 = y[(size_t)s1 * 32 + t];
        uint32_t u2 = y[(size_t)s2 * 32 + t];
        uint32_t u3 = y[(size_t)s3 * 32 + t];
        a0 += (bfu_lo(u0) + bfu_lo(u1)) + (bfu_lo(u2) + bfu_lo(u3));
        a1 += (bfu_hi(u0) + bfu_hi(u1)) + (bfu_hi(u2) + bfu_hi(u3));
    }
    for (; i < e; ++i) {
        uint32_t u = y[(size_t)esrc[i] * 32 + t];
        a0 += bfu_lo(u);
        a1 += bfu_hi(u);
    }
    float cd = (e > b) ? rsqrtf((float)(e - b)) : 0.f;
    float2 o;
    o.x = fmaxf(a0 * cd + bias[t * 2], 0.f);
    o.y = fmaxf(a1 * cd + bias[t * 2 + 1], 0.f);
    *(float2*)(out + (size_t)row * 64 + t * 2) = o;
}

extern "C" void kernel_launch(void* const* d_in, const int* in_sizes, int n_in,
                              void* d_out, int out_size, void* d_ws, size_t ws_size,
                              hipStream_t stream) {
    const float* x    = (const float*)d_in[0];
    const int*   src0 = (const int*)d_in[1];
    const int*   dst0 = (const int*)d_in[2];
    const int*   src1 = (const int*)d_in[3];
    const int*   dst1 = (const int*)d_in[4];
    const float* W0   = (const float*)d_in[5];
    const float* b0   = (const float*)d_in[6];
    const float* W1   = (const float*)d_in[7];
    const float* b1   = (const float*)d_in[8];
    float* out = (float*)d_out;

    const int E0 = in_sizes[1];
    const int E1 = in_sizes[3];
    const int M_PAD = 100096;   // 782 * 128

    char* p = (char*)d_ws;
    auto alloc = [&](size_t bytes) {
        char* r = p;
        p += (bytes + 511) & ~(size_t)511;
        return r;
    };
    int*   odeg0 = (int*)alloc((size_t)N_SRC0 * 4);
    float* cs0   = (float*)alloc((size_t)N_SRC0 * 4);
    int*   cnt0  = (int*)alloc((size_t)N_DST0 * 4);
    int*   cur0  = (int*)alloc((size_t)N_DST0 * 4);
    int*   off0  = (int*)alloc((size_t)(N_DST0 + 1) * 4);
    int*   sums0 = (int*)alloc(128 * 4);
    int*   odeg1 = (int*)alloc((size_t)N_DST0 * 4);
    float* cs1   = (float*)alloc((size_t)N_DST0 * 4);
    int*   cnt1  = (int*)alloc((size_t)N_DST1 * 4);
    int*   cur1  = (int*)alloc((size_t)N_DST1 * 4);
    int*   off1  = (int*)alloc((size_t)(N_DST1 + 1) * 4);
    int*   sums1 = (int*)alloc(128 * 4);
    int*   esrc0 = (int*)alloc((size_t)E0 * 4);
    int*   esrc1 = (int*)alloc((size_t)E1 * 4);
    unsigned short* W0p = (unsigned short*)alloc((size_t)32768 * 2);
    unsigned short* W1p = (unsigned short*)alloc((size_t)16384 * 2);
    // big region A: xs (400000*128 bf16 = 102.4MB), later reused as h0b (M_PAD*256 bf16 = 51.2MB)
    char* regA = alloc((size_t)N_SRC0 * 128 * 2);
    // big region B: aggb (100000*128 bf16 = 25.6MB), later reused as y1b (100000*64 bf16 = 12.8MB)
    char* regB = alloc((size_t)N_DST0 * 128 * 2);

    uint32_t* xs   = (uint32_t*)regA;        // [N_SRC0][64] dwords
    unsigned short* h0b = (unsigned short*)regA;  // [M_PAD][256] bf16 (xs dead by then)
    uint32_t* aggb = (uint32_t*)regB;        // [N_DST0][64] dwords
    unsigned short* y1b = (unsigned short*)regB;  // [N_DST0][64] bf16 (aggb dead by then)

    // zero counters (graph replays reuse ws)
    hipMemsetAsync(odeg0, 0, (size_t)N_SRC0 * 4, stream);
    hipMemsetAsync(cnt0,  0, (size_t)N_DST0 * 4, stream);
    hipMemsetAsync(cur0,  0, (size_t)N_DST0 * 4, stream);
    hipMemsetAsync(odeg1, 0, (size_t)N_DST0 * 4, stream);
    hipMemsetAsync(cnt1,  0, (size_t)N_DST1 * 4, stream);
    hipMemsetAsync(cur1,  0, (size_t)N_DST1 * 4, stream);

    // degrees
    count2_kernel<<<(E0 + 255) / 256, 256, 0, stream>>>(src0, dst0, odeg0, cnt0, E0);
    count2_kernel<<<(E1 + 255) / 256, 256, 0, stream>>>(src1, dst1, odeg1, cnt1, E1);
    rsqrt_kernel<<<(N_SRC0 + 255) / 256, 256, 0, stream>>>(odeg0, cs0, N_SRC0);
    rsqrt_kernel<<<(N_DST0 + 255) / 256, 256, 0, stream>>>(odeg1, cs1, N_DST0);

    // weight packs (independent)
    packW0_kernel<<<128, 256, 0, stream>>>(W0, W0p);
    packW1_kernel<<<64, 256, 0, stream>>>(W1, W1p);

    // prescale x -> bf16
    prescale_kernel<<<N_SRC0 * 32 / 256, 256, 0, stream>>>((const float4*)x, cs0, (uint2*)xs);

    // CSR offsets
    const int nb0 = (N_DST0 + SCAN_TILE - 1) / SCAN_TILE;
    const int nb1 = (N_DST1 + SCAN_TILE - 1) / SCAN_TILE;
    scan1_kernel<<<nb0, SCAN_BLOCK, 0, stream>>>(cnt0, off0, sums0, N_DST0);
    scan2_kernel<<<1, 128, 0, stream>>>(sums0, nb0);
    scan3_kernel<<<(N_DST0 + 255) / 256, 256, 0, stream>>>(off0, sums0, N_DST0, E0);
    scan1_kernel<<<nb1, SCAN_BLOCK, 0, stream>>>(cnt1, off1, sums1, N_DST1);
    scan2_kernel<<<1, 128, 0, stream>>>(sums1, nb1);
    scan3_kernel<<<(N_DST1 + 255) / 256, 256, 0, stream>>>(off1, sums1, N_DST1, E1);

    // bucket fill
    fill_kernel<<<(E0 + 255) / 256, 256, 0, stream>>>(src0, dst0, off0, cur0, esrc0, E0);
    fill_kernel<<<(E1 + 255) / 256, 256, 0, stream>>>(src1, dst1, off1, cur1, esrc1, E1);

    // layer 0
    agg0_kernel<<<N_DST0 / 4, 256, 0, stream>>>(xs, esrc0, off0, aggb, N_DST0);
    gemm0_mfma<<<N_DST0 / 32, 256, 0, stream>>>((const short*)aggb, (const short*)W0p, b0, h0b);

    // layer 1
    gemmt_mfma<<<M_PAD / 128, 256, 0, stream>>>((const short*)h0b, (const short*)W1p, cs1, y1b, N_DST0);
    agg1_kernel<<<N_DST1 / 8, 256, 0, stream>>>((const uint32_t*)y1b, esrc1, off1, b1, out, N_DST1);
}

// Round 4
// 804.857 us; speedup vs baseline: 10.6957x; 1.0179x over previous
//
#include <hip/hip_runtime.h>
#include <hip/hip_bf16.h>
#include <stdint.h>

#define N_SRC0 400000
#define N_DST0 100000
#define N_DST1 25000
#define NX 8

typedef __attribute__((ext_vector_type(8))) short short8;
typedef __attribute__((ext_vector_type(4))) float f32x4;

__device__ __forceinline__ unsigned short f2bf(float f) {
    __hip_bfloat16 h = __float2bfloat16(f);
    union { __hip_bfloat16 h; unsigned short u; } c;
    c.h = h;
    return c.u;
}
__device__ __forceinline__ float bfu_lo(uint32_t u) { return __uint_as_float(u << 16); }
__device__ __forceinline__ float bfu_hi(uint32_t u) { return __uint_as_float(u & 0xffff0000u); }
__device__ __forceinline__ uint32_t packbf2(float a, float b) {
    return (uint32_t)f2bf(a) | ((uint32_t)f2bf(b) << 16);
}

// physical XCD id (gfx940+); workgroup runs on exactly one XCD
__device__ __forceinline__ int xcc_id() {
    unsigned x;
    asm volatile("s_getreg_b32 %0, hwreg(HW_REG_XCC_ID)" : "=s"(x));
    return (int)(x & (NX - 1));
}

// L2-local (XCD-local) atomic: workgroup scope => no fabric round-trip.
// Safe because each privatized copy is only ever touched by its own XCD.
__device__ __forceinline__ void xcd_atomic_inc(int* p) {
    __hip_atomic_fetch_add(p, 1, __ATOMIC_RELAXED, __HIP_MEMORY_SCOPE_WORKGROUP);
}
__device__ __forceinline__ int xcd_atomic_inc_ret(int* p) {
    return __hip_atomic_fetch_add(p, 1, __ATOMIC_RELAXED, __HIP_MEMORY_SCOPE_WORKGROUP);
}

// ---------------- degree histograms into per-XCD copies ----------------
__global__ void countx_kernel(const int* __restrict__ src, const int* __restrict__ dst,
                              int* __restrict__ O, int* __restrict__ C,
                              int nsb, int ndb, int n) {
    int i = blockIdx.x * blockDim.x + threadIdx.x;
    if (i >= n) return;
    int x = xcc_id();
    xcd_atomic_inc(&O[(size_t)x * nsb + src[i]]);
    xcd_atomic_inc(&C[(size_t)x * ndb + dst[i]]);
}

// cs[i] = rsqrt(sum over copies) or 0
__global__ void merge_rsqrt_kernel(const int* __restrict__ O, float* __restrict__ cs, int nbins) {
    int i = blockIdx.x * blockDim.x + threadIdx.x;
    if (i >= nbins) return;
    int s = 0;
    #pragma unroll
    for (int x = 0; x < NX; ++x) s += O[(size_t)x * nbins + i];
    cs[i] = s > 0 ? rsqrtf((float)s) : 0.f;
}

// ---------------- two-level exclusive scan over [d][x] ordering ----------------
#define SCAN_BLOCK 256
#define SCAN_ITEMS 4
#define SCAN_TILE (SCAN_BLOCK * SCAN_ITEMS)

// scans n = nbins*NX elements; element j=(d*NX+x) reads C[x*nbins+d]
__global__ __launch_bounds__(SCAN_BLOCK) void scan1x_kernel(
        const int* __restrict__ C, int* __restrict__ offx,
        int* __restrict__ sums, int nbins) {
    __shared__ int lds[SCAN_BLOCK];
    const int n = nbins * NX;
    const int tid = threadIdx.x;
    const int base = blockIdx.x * SCAN_TILE + tid * SCAN_ITEMS;
    int v[SCAN_ITEMS];
    int run = 0;
    #pragma unroll
    for (int i = 0; i < SCAN_ITEMS; ++i) {
        int j = base + i;
        int t = 0;
        if (j < n) t = C[(size_t)(j & (NX - 1)) * nbins + (j >> 3)];
        v[i] = run;
        run += t;
    }
    lds[tid] = run;
    __syncthreads();
    int incl = run;
    for (int off = 1; off < SCAN_BLOCK; off <<= 1) {
        int u = (tid >= off) ? lds[tid - off] : 0;
        __syncthreads();
        incl += u;
        lds[tid] = incl;
        __syncthreads();
    }
    if (tid == SCAN_BLOCK - 1) sums[blockIdx.x] = incl;
    int excl = incl - run;
    #pragma unroll
    for (int i = 0; i < SCAN_ITEMS; ++i)
        if (base + i < n) offx[base + i] = excl + v[i];
}

// single-block exclusive scan of up to 1024 block sums
__global__ __launch_bounds__(256) void scan2_kernel(int* __restrict__ sums, int nb) {
    __shared__ int lds[256];
    const int tid = threadIdx.x;
    const int base = tid * 4;
    int v[4];
    int run = 0;
    #pragma unroll
    for (int i = 0; i < 4; ++i) {
        int t = (base + i < nb) ? sums[base + i] : 0;
        v[i] = run;
        run += t;
    }
    lds[tid] = run;
    __syncthreads();
    int incl = run;
    for (int off = 1; off < 256; off <<= 1) {
        int u = (tid >= off) ? lds[tid - off] : 0;
        __syncthreads();
        incl += u;
        lds[tid] = incl;
        __syncthreads();
    }
    int excl = incl - run;
    #pragma unroll
    for (int i = 0; i < 4; ++i)
        if (base + i < nb) sums[base + i] = excl + v[i];
}

__global__ void scan3_kernel(int* __restrict__ out, const int* __restrict__ sums, int n) {
    int i = blockIdx.x * blockDim.x + threadIdx.x;
    if (i < n) out[i] += sums[i / SCAN_TILE];
}

// off[d] = offx[d*NX]; off[nbins] = total
__global__ void extract_off_kernel(const int* __restrict__ offx, int* __restrict__ off,
                                   int nbins, int total) {
    int d = blockIdx.x * blockDim.x + threadIdx.x;
    if (d < nbins) off[d] = offx[(size_t)d * NX];
    if (d == nbins) off[d] = total;
}

// ---------------- CSR bucket fill with XCD-local cursors ----------------
__global__ void fillx_kernel(const int* __restrict__ src, const int* __restrict__ dst,
                             const int* __restrict__ offx, int* __restrict__ cur,
                             int* __restrict__ esrc, int ndb, int n) {
    int i = blockIdx.x * blockDim.x + threadIdx.x;
    if (i >= n) return;
    int x = xcc_id();
    int d = dst[i];
    int r = xcd_atomic_inc_ret(&cur[(size_t)x * ndb + d]);
    esrc[offx[(size_t)d * NX + x] + r] = src[i];
}

// ---------------- prescale: xs = bf16(x * cs0), [N_SRC0,128] ----------------
__global__ __launch_bounds__(256) void prescale_kernel(
        const float4* __restrict__ x4, const float* __restrict__ cs,
        uint2* __restrict__ xs) {
    int id = blockIdx.x * 256 + threadIdx.x;
    int row = id >> 5;
    float c = cs[row];
    float4 v = x4[id];
    uint2 o;
    o.x = packbf2(v.x * c, v.y * c);
    o.y = packbf2(v.z * c, v.w * c);
    xs[id] = o;
}

// ---------------- weight pack: Bp[kt][n][kk] = bf16(W[kt*32+kk][n]) ----------
__global__ void packW0_kernel(const float* __restrict__ W, unsigned short* __restrict__ Bp) {
    int id = blockIdx.x * 256 + threadIdx.x;       // 4*256*32 = 32768
    int kk = id & 31, n = (id >> 5) & 255, kt = id >> 13;
    Bp[id] = f2bf(W[(kt * 32 + kk) * 256 + n]);
}
__global__ void packW1_kernel(const float* __restrict__ W, unsigned short* __restrict__ Bp) {
    int id = blockIdx.x * 256 + threadIdx.x;       // 8*64*32 = 16384
    int kk = id & 31, n = (id >> 5) & 63, kt = id >> 11;
    Bp[id] = f2bf(W[(kt * 32 + kk) * 64 + n]);
}

// ---------------- layer-0 aggregation: 64 threads/row, bf16 gather ----------
__global__ __launch_bounds__(256) void agg0_kernel(
        const uint32_t* __restrict__ xs, const int* __restrict__ esrc,
        const int* __restrict__ off, uint32_t* __restrict__ aggb, int nrows) {
    int row = blockIdx.x * 4 + (threadIdx.x >> 6);
    int t = threadIdx.x & 63;
    if (row >= nrows) return;
    int b = off[row], e = off[row + 1];
    float a0 = 0.f, a1 = 0.f;
    int i = b;
    for (; i + 7 < e; i += 8) {
        int s0 = esrc[i],     s1 = esrc[i + 1], s2 = esrc[i + 2], s3 = esrc[i + 3];
        int s4 = esrc[i + 4], s5 = esrc[i + 5], s6 = esrc[i + 6], s7 = esrc[i + 7];
        uint32_t u0 = xs[(size_t)s0 * 64 + t];
        uint32_t u1 = xs[(size_t)s1 * 64 + t];
        uint32_t u2 = xs[(size_t)s2 * 64 + t];
        uint32_t u3 = xs[(size_t)s3 * 64 + t];
        uint32_t u4 = xs[(size_t)s4 * 64 + t];
        uint32_t u5 = xs[(size_t)s5 * 64 + t];
        uint32_t u6 = xs[(size_t)s6 * 64 + t];
        uint32_t u7 = xs[(size_t)s7 * 64 + t];
        a0 += ((bfu_lo(u0) + bfu_lo(u1)) + (bfu_lo(u2) + bfu_lo(u3)))
            + ((bfu_lo(u4) + bfu_lo(u5)) + (bfu_lo(u6) + bfu_lo(u7)));
        a1 += ((bfu_hi(u0) + bfu_hi(u1)) + (bfu_hi(u2) + bfu_hi(u3)))
            + ((bfu_hi(u4) + bfu_hi(u5)) + (bfu_hi(u6) + bfu_hi(u7)));
    }
    for (; i < e; ++i) {
        uint32_t u = xs[(size_t)esrc[i] * 64 + t];
        a0 += bfu_lo(u);
        a1 += bfu_hi(u);
    }
    float cd = (e > b) ? rsqrtf((float)(e - b)) : 0.f;
    aggb[(size_t)row * 64 + t] = packbf2(a0 * cd, a1 * cd);
}

// ---------------- GEMM0 (MFMA): h = relu(agg @ W0 + b0), bf16 out ----------
__global__ __launch_bounds__(256) void gemm0_mfma(
        const short* __restrict__ A,            // [N_DST0][128] bf16
        const short* __restrict__ Bp,           // [4][256][32] bf16
        const float* __restrict__ bias,         // [256]
        unsigned short* __restrict__ H) {       // [>=N_DST0][256] bf16
    const int w = threadIdx.x >> 6;
    const int l = threadIdx.x & 63;
    const int rbase = blockIdx.x * 32;
    const int cbase = w * 64;
    const int lr = l & 15;
    const int lk = (l >> 4) * 8;
    f32x4 acc[2][4] = {};
    #pragma unroll
    for (int kt = 0; kt < 4; ++kt) {
        short8 a[2], b[4];
        #pragma unroll
        for (int rt = 0; rt < 2; ++rt)
            a[rt] = *(const short8*)(A + (size_t)(rbase + rt * 16 + lr) * 128 + kt * 32 + lk);
        #pragma unroll
        for (int ct = 0; ct < 4; ++ct)
            b[ct] = *(const short8*)(Bp + (size_t)(kt * 256 + cbase + ct * 16 + lr) * 32 + lk);
        #pragma unroll
        for (int rt = 0; rt < 2; ++rt)
            #pragma unroll
            for (int ct = 0; ct < 4; ++ct)
                acc[rt][ct] = __builtin_amdgcn_mfma_f32_16x16x32_bf16(a[rt], b[ct], acc[rt][ct], 0, 0, 0);
    }
    const int orow0 = (l >> 4) * 4;
    #pragma unroll
    for (int rt = 0; rt < 2; ++rt) {
        #pragma unroll
        for (int ct = 0; ct < 4; ++ct) {
            int col = cbase + ct * 16 + lr;
            float bv = bias[col];
            #pragma unroll
            for (int j = 0; j < 4; ++j) {
                int row = rbase + rt * 16 + orow0 + j;
                float v = fmaxf(acc[rt][ct][j] + bv, 0.f);
                H[(size_t)row * 256 + col] = f2bf(v);
            }
        }
    }
}

// ---------------- GEMM-T (MFMA): y = (h0 @ W1) * cs1[row], bf16 out --------
__global__ __launch_bounds__(256) void gemmt_mfma(
        const short* __restrict__ A,            // [M_PAD][256] bf16
        const short* __restrict__ Bp,           // [8][64][32] bf16
        const float* __restrict__ cs1,          // [N_DST0]
        unsigned short* __restrict__ Y,         // [N_DST0][64] bf16
        int M) {
    const int w = threadIdx.x >> 6;
    const int l = threadIdx.x & 63;
    const int rbase = blockIdx.x * 128 + w * 32;
    const int lr = l & 15;
    const int lk = (l >> 4) * 8;
    f32x4 acc[2][4] = {};
    #pragma unroll
    for (int kt = 0; kt < 8; ++kt) {
        short8 a[2], b[4];
        #pragma unroll
        for (int rt = 0; rt < 2; ++rt)
            a[rt] = *(const short8*)(A + (size_t)(rbase + rt * 16 + lr) * 256 + kt * 32 + lk);
        #pragma unroll
        for (int ct = 0; ct < 4; ++ct)
            b[ct] = *(const short8*)(Bp + (size_t)(kt * 64 + ct * 16 + lr) * 32 + lk);
        #pragma unroll
        for (int rt = 0; rt < 2; ++rt)
            #pragma unroll
            for (int ct = 0; ct < 4; ++ct)
                acc[rt][ct] = __builtin_amdgcn_mfma_f32_16x16x32_bf16(a[rt], b[ct], acc[rt][ct], 0, 0, 0);
    }
    const int orow0 = (l >> 4) * 4;
    #pragma unroll
    for (int rt = 0; rt < 2; ++rt) {
        #pragma unroll
        for (int j = 0; j < 4; ++j) {
            int row = rbase + rt * 16 + orow0 + j;
            if (row < M) {
                float c = cs1[row];
                #pragma unroll
                for (int ct = 0; ct < 4; ++ct) {
                    int col = ct * 16 + lr;
                    Y[(size_t)row * 64 + col] = f2bf(acc[rt][ct][j] * c);
                }
            }
        }
    }
}

// ---------------- layer-1 aggregation: 32 threads/row, +bias, relu ---------
__global__ __launch_bounds__(256) void agg1_kernel(
        const uint32_t* __restrict__ y, const int* __restrict__ esrc,
        const int* __restrict__ off, const float* __restrict__ bias,
        float* __restrict__ out, int nrows) {
    int row = blockIdx.x * 8 + (threadIdx.x >> 5);
    int t = threadIdx.x & 31;
    if (row >= nrows) return;
    int b = off[row], e = off[row + 1];
    float a0 = 0.f, a1 = 0.f;
    int i = b;
    for (; i + 3 < e; i += 4) {
        int s0 = esrc[i], s1 = esrc[i + 1], s2 = esrc[i + 2], s3 = esrc[i + 3];
        uint32_t u0 = y[(size_t)s0 * 32 + t];
        uint32_t u1 = y[(size_t)s1 * 32 + t];
        uint32_t u2 = y[(size_t)s2 * 32 + t];
        uint32_t u3 = y[(size_t)s3 * 32 + t];
        a0 += (bfu_lo(u0) + bfu_lo(u1)) + (bfu_lo(u2) + bfu_lo(u3));
        a1 += (bfu_hi(u0) + bfu_hi(u1)) + (bfu_hi(u2) + bfu_hi(u3));
    }
    for (; i < e; ++i) {
        uint32_t u = y[(size_t)esrc[i] * 32 + t];
        a0 += bfu_lo(u);
        a1 += bfu_hi(u);
    }
    float cd = (e > b) ? rsqrtf((float)(e - b)) : 0.f;
    float2 o;
    o.x = fmaxf(a0 * cd + bias[t * 2], 0.f);
    o.y = fmaxf(a1 * cd + bias[t * 2 + 1], 0.f);
    *(float2*)(out + (size_t)row * 64 + t * 2) = o;
}

extern "C" void kernel_launch(void* const* d_in, const int* in_sizes, int n_in,
                              void* d_out, int out_size, void* d_ws, size_t ws_size,
                              hipStream_t stream) {
    const float* x    = (const float*)d_in[0];
    const int*   src0 = (const int*)d_in[1];
    const int*   dst0 = (const int*)d_in[2];
    const int*   src1 = (const int*)d_in[3];
    const int*   dst1 = (const int*)d_in[4];
    const float* W0   = (const float*)d_in[5];
    const float* b0   = (const float*)d_in[6];
    const float* W1   = (const float*)d_in[7];
    const float* b1   = (const float*)d_in[8];
    float* out = (float*)d_out;

    const int E0 = in_sizes[1];
    const int E1 = in_sizes[3];
    const int M_PAD = 100096;   // 782 * 128

    char* p = (char*)d_ws;
    auto alloc = [&](size_t bytes) {
        char* r = p;
        p += (bytes + 511) & ~(size_t)511;
        return r;
    };
    // ---- zero-initialized block (contiguous, single memset) ----
    char* zbase = p;
    int* O0   = (int*)alloc((size_t)NX * N_SRC0 * 4);   // 12.8 MB
    int* C0   = (int*)alloc((size_t)NX * N_DST0 * 4);   //  3.2 MB
    int* O1   = (int*)alloc((size_t)NX * N_DST0 * 4);   //  3.2 MB
    int* C1   = (int*)alloc((size_t)NX * N_DST1 * 4);   //  0.8 MB
    int* cur0 = (int*)alloc((size_t)NX * N_DST0 * 4);   //  3.2 MB
    int* cur1 = (int*)alloc((size_t)NX * N_DST1 * 4);   //  0.8 MB
    size_t zbytes = (size_t)(p - zbase);
    // ---- rest ----
    float* cs0   = (float*)alloc((size_t)N_SRC0 * 4);
    float* cs1   = (float*)alloc((size_t)N_DST0 * 4);
    int*   offx0 = (int*)alloc((size_t)NX * N_DST0 * 4);
    int*   offx1 = (int*)alloc((size_t)NX * N_DST1 * 4);
    int*   off0  = (int*)alloc((size_t)(N_DST0 + 1) * 4);
    int*   off1  = (int*)alloc((size_t)(N_DST1 + 1) * 4);
    int*   sums0 = (int*)alloc(1024 * 4);
    int*   sums1 = (int*)alloc(1024 * 4);
    int*   esrc0 = (int*)alloc((size_t)E0 * 4);
    int*   esrc1 = (int*)alloc((size_t)E1 * 4);
    unsigned short* W0p = (unsigned short*)alloc((size_t)32768 * 2);
    unsigned short* W1p = (unsigned short*)alloc((size_t)16384 * 2);
    char* regA = alloc((size_t)N_SRC0 * 128 * 2);   // xs, later h0b
    char* regB = alloc((size_t)N_DST0 * 128 * 2);   // aggb, later y1b

    uint32_t* xs   = (uint32_t*)regA;
    unsigned short* h0b = (unsigned short*)regA;
    uint32_t* aggb = (uint32_t*)regB;
    unsigned short* y1b = (unsigned short*)regB;

    hipMemsetAsync(zbase, 0, zbytes, stream);

    // per-XCD degree histograms
    countx_kernel<<<(E0 + 255) / 256, 256, 0, stream>>>(src0, dst0, O0, C0, N_SRC0, N_DST0, E0);
    countx_kernel<<<(E1 + 255) / 256, 256, 0, stream>>>(src1, dst1, O1, C1, N_DST0, N_DST1, E1);
    merge_rsqrt_kernel<<<(N_SRC0 + 255) / 256, 256, 0, stream>>>(O0, cs0, N_SRC0);
    merge_rsqrt_kernel<<<(N_DST0 + 255) / 256, 256, 0, stream>>>(O1, cs1, N_DST0);

    // weight packs
    packW0_kernel<<<128, 256, 0, stream>>>(W0, W0p);
    packW1_kernel<<<64, 256, 0, stream>>>(W1, W1p);

    // prescale x -> bf16
    prescale_kernel<<<N_SRC0 * 32 / 256, 256, 0, stream>>>((const float4*)x, cs0, (uint2*)xs);

    // CSR offsets over [d][x] ordering
    const int n0x = N_DST0 * NX, n1x = N_DST1 * NX;
    const int nb0 = (n0x + SCAN_TILE - 1) / SCAN_TILE;   // 782
    const int nb1 = (n1x + SCAN_TILE - 1) / SCAN_TILE;   // 196
    scan1x_kernel<<<nb0, SCAN_BLOCK, 0, stream>>>(C0, offx0, sums0, N_DST0);
    scan2_kernel<<<1, 256, 0, stream>>>(sums0, nb0);
    scan3_kernel<<<(n0x + 255) / 256, 256, 0, stream>>>(offx0, sums0, n0x);
    extract_off_kernel<<<(N_DST0 + 256) / 256, 256, 0, stream>>>(offx0, off0, N_DST0, E0);
    scan1x_kernel<<<nb1, SCAN_BLOCK, 0, stream>>>(C1, offx1, sums1, N_DST1);
    scan2_kernel<<<1, 256, 0, stream>>>(sums1, nb1);
    scan3_kernel<<<(n1x + 255) / 256, 256, 0, stream>>>(offx1, sums1, n1x);
    extract_off_kernel<<<(N_DST1 + 256) / 256, 256, 0, stream>>>(offx1, off1, N_DST1, E1);

    // bucket fill (XCD-local cursors; d-major esrc layout preserved)
    fillx_kernel<<<(E0 + 255) / 256, 256, 0, stream>>>(src0, dst0, offx0, cur0, esrc0, N_DST0, E0);
    fillx_kernel<<<(E1 + 255) / 256, 256, 0, stream>>>(src1, dst1, offx1, cur1, esrc1, N_DST1, E1);

    // layer 0
    agg0_kernel<<<N_DST0 / 4, 256, 0, stream>>>(xs, esrc0, off0, aggb, N_DST0);
    gemm0_mfma<<<N_DST0 / 32, 256, 0, stream>>>((const short*)aggb, (const short*)W0p, b0, h0b);

    // layer 1
    gemmt_mfma<<<M_PAD / 128, 256, 0, stream>>>((const short*)h0b, (const short*)W1p, cs1, y1b, N_DST0);
    agg1_kernel<<<N_DST1 / 8, 256, 0, stream>>>((const uint32_t*)y1b, esrc1, off1, b1, out, N_DST1);
}

// Round 5
// 467.672 us; speedup vs baseline: 18.4072x; 1.7210x over previous
//
#include <hip/hip_runtime.h>
#include <hip/hip_bf16.h>
#include <stdint.h>

#define N_SRC0 400000
#define N_DST0 100000
#define N_DST1 25000

// coarse-bucket geometry (all static: node counts are fixed)
#define SH_D0 9
#define NK_D0 196      // ceil(100000/512)
#define SH_S0 9
#define NK_S0 782      // ceil(400000/512)
#define SH_D1 8
#define NK_D1 98       // ceil(25000/256)
#define SH_S1 9
#define NK_S1 196      // ceil(100000/512)
#define NB0 1024       // partition blocks, layer-0 edges
#define NB1 256        // partition blocks, layer-1 edges

// bh (block-histogram) concatenated layout offsets
#define BH_D0 0
#define BH_S0 (NK_D0 * NB0)                    // 200704
#define BH_D1 (BH_S0 + NK_S0 * NB0)            // 1001472
#define BH_S1 (BH_D1 + NK_D1 * NB1)            // 1026560
#define BH_TOT (BH_S1 + NK_S1 * NB1)           // 1076736

typedef __attribute__((ext_vector_type(8))) short short8;
typedef __attribute__((ext_vector_type(4))) float f32x4;

__device__ __forceinline__ unsigned short f2bf(float f) {
    __hip_bfloat16 h = __float2bfloat16(f);
    union { __hip_bfloat16 h; unsigned short u; } c;
    c.h = h;
    return c.u;
}
__device__ __forceinline__ float bfu_lo(uint32_t u) { return __uint_as_float(u << 16); }
__device__ __forceinline__ float bfu_hi(uint32_t u) { return __uint_as_float(u & 0xffff0000u); }
__device__ __forceinline__ uint32_t packbf2(float a, float b) {
    return (uint32_t)f2bf(a) | ((uint32_t)f2bf(b) << 16);
}

// ============ pass 1: per-block coarse histograms (src & dst fused) ============
// h layout in LDS: [dnb dst bins][snb src bins]; bh writes bucket-major [bkt][blk]
__global__ __launch_bounds__(256) void part_hist2(
        const int* __restrict__ src, const int* __restrict__ dst, int n,
        int sshift, int snb, int dshift, int dnb, int NB,
        int* __restrict__ bhd, int* __restrict__ bhs) {
    extern __shared__ int h[];
    const int blk = blockIdx.x;
    for (int i = threadIdx.x; i < dnb + snb; i += 256) h[i] = 0;
    __syncthreads();
    const int per = (n + NB - 1) / NB;
    const int b = blk * per;
    const int e = min(b + per, n);
    for (int i = b + threadIdx.x; i < e; i += 256) {
        atomicAdd(&h[dst[i] >> dshift], 1);
        atomicAdd(&h[dnb + (src[i] >> sshift)], 1);
    }
    __syncthreads();
    for (int i = threadIdx.x; i < dnb; i += 256) bhd[(size_t)i * NB + blk] = h[i];
    for (int i = threadIdx.x; i < snb; i += 256) bhs[(size_t)i * NB + blk] = h[dnb + i];
}

// ============ global exclusive scan over bh (n = BH_TOT) ============
#define SCAN_ITEMS 8
#define SCAN_TILE 2048

__global__ __launch_bounds__(256) void scan1_kernel(
        const int* __restrict__ in, int* __restrict__ out,
        int* __restrict__ sums, int n) {
    __shared__ int lds[256];
    const int tid = threadIdx.x;
    const int base = blockIdx.x * SCAN_TILE + tid * SCAN_ITEMS;
    int v[SCAN_ITEMS];
    int run = 0;
    #pragma unroll
    for (int i = 0; i < SCAN_ITEMS; ++i) {
        int t = (base + i < n) ? in[base + i] : 0;
        v[i] = run;
        run += t;
    }
    lds[tid] = run;
    __syncthreads();
    int incl = run;
    for (int off = 1; off < 256; off <<= 1) {
        int u = (tid >= off) ? lds[tid - off] : 0;
        __syncthreads();
        incl += u;
        lds[tid] = incl;
        __syncthreads();
    }
    if (tid == 255) sums[blockIdx.x] = incl;
    int excl = incl - run;
    #pragma unroll
    for (int i = 0; i < SCAN_ITEMS; ++i)
        if (base + i < n) out[base + i] = excl + v[i];
}

__global__ __launch_bounds__(256) void scan2_kernel(int* __restrict__ sums, int nb) {
    __shared__ int lds[256];
    const int tid = threadIdx.x;
    const int base = tid * 4;
    int v[4];
    int run = 0;
    #pragma unroll
    for (int i = 0; i < 4; ++i) {
        int t = (base + i < nb) ? sums[base + i] : 0;
        v[i] = run;
        run += t;
    }
    lds[tid] = run;
    __syncthreads();
    int incl = run;
    for (int off = 1; off < 256; off <<= 1) {
        int u = (tid >= off) ? lds[tid - off] : 0;
        __syncthreads();
        incl += u;
        lds[tid] = incl;
        __syncthreads();
    }
    int excl = incl - run;
    #pragma unroll
    for (int i = 0; i < 4; ++i)
        if (base + i < nb) sums[base + i] = excl + v[i];
}

__global__ void scan3_kernel(int* __restrict__ out, const int* __restrict__ sums, int n) {
    int i = blockIdx.x * blockDim.x + threadIdx.x;
    if (i < n) out[i] += sums[i / SCAN_TILE];
}

// ============ pass 2: scatter to bucket-major staging (both keys fused) ============
// stg entry: (key << 32) | payload. dst-keyed: payload = src. src-keyed: payload = 0.
__global__ __launch_bounds__(256) void part_scat2(
        const int* __restrict__ src, const int* __restrict__ dst, int n,
        int sshift, int snb, int dshift, int dnb, int NB,
        const int* __restrict__ bhd, const int* __restrict__ bhs,
        uint64_t* __restrict__ stg) {
    extern __shared__ int cur[];
    const int blk = blockIdx.x;
    for (int i = threadIdx.x; i < dnb; i += 256) cur[i] = bhd[(size_t)i * NB + blk];
    for (int i = threadIdx.x; i < snb; i += 256) cur[dnb + i] = bhs[(size_t)i * NB + blk];
    __syncthreads();
    const int per = (n + NB - 1) / NB;
    const int b = blk * per;
    const int e = min(b + per, n);
    for (int i = b + threadIdx.x; i < e; i += 256) {
        int s = src[i], d = dst[i];
        int pd = atomicAdd(&cur[d >> dshift], 1);
        stg[pd] = ((uint64_t)(uint32_t)d << 32) | (uint32_t)s;
        int ps = atomicAdd(&cur[dnb + (s >> sshift)], 1);
        stg[ps] = ((uint64_t)(uint32_t)s << 32);
    }
}

// ============ pass 3a: per-bucket fine CSR (off + esrc) ============
// grid = nbkt; bucket k covers bins [k<<shift, (k+1)<<shift)
__global__ __launch_bounds__(256) void fine_csr(
        const uint64_t* __restrict__ stg, const int* __restrict__ bhs,
        int NB, int shift, int nbins, int total, int rel,
        int* __restrict__ off, int* __restrict__ esrc) {
    __shared__ int fine[512];
    __shared__ int part[256];
    const int k = blockIdx.x;
    const int fb = 1 << shift;
    const int base = bhs[(size_t)k * NB];
    const int end = (k + 1 < gridDim.x) ? bhs[(size_t)(k + 1) * NB] : total;
    const int gb = k << shift;
    const int t = threadIdx.x;
    for (int i = t; i < fb; i += 256) fine[i] = 0;
    __syncthreads();
    for (int i = base + t; i < end; i += 256)
        atomicAdd(&fine[(int)(stg[i] >> 32) - gb], 1);
    __syncthreads();
    // exclusive scan of fine[0..fb) (fb <= 512), 2 slots/thread
    int a0 = (2 * t < fb) ? fine[2 * t] : 0;
    int a1 = (2 * t + 1 < fb) ? fine[2 * t + 1] : 0;
    part[t] = a0 + a1;
    __syncthreads();
    int incl = part[t];
    for (int o = 1; o < 256; o <<= 1) {
        int u = (t >= o) ? part[t - o] : 0;
        __syncthreads();
        incl += u;
        part[t] = incl;
        __syncthreads();
    }
    int excl = incl - (a0 + a1);
    if (2 * t < fb) fine[2 * t] = excl;
    if (2 * t + 1 < fb) fine[2 * t + 1] = excl + a0;
    __syncthreads();
    // write off (global positions relative to this layer's esrc)
    const int rb = base - rel;
    for (int i = t; i < fb; i += 256) {
        int g = gb + i;
        if (g < nbins) off[g] = rb + fine[i];
    }
    if (k == gridDim.x - 1 && t == 0) off[nbins] = total - rel;
    __syncthreads();
    // scatter srcs into esrc, bin-major within bucket (fine[] now = running cursors)
    for (int i = base + t; i < end; i += 256) {
        uint64_t pr = stg[i];
        int d = (int)(pr >> 32);
        int p = atomicAdd(&fine[d - gb], 1);
        esrc[rb + p] = (int)(uint32_t)pr;
    }
}

// ============ pass 3b: per-bucket fine histogram -> cs = rsqrt(deg) ============
__global__ __launch_bounds__(256) void fine_hist(
        const uint64_t* __restrict__ stg, const int* __restrict__ bhs,
        int NB, int shift, int nbins, int total, float* __restrict__ cs) {
    __shared__ int fine[512];
    const int k = blockIdx.x;
    const int fb = 1 << shift;
    const int base = bhs[(size_t)k * NB];
    const int end = (k + 1 < gridDim.x) ? bhs[(size_t)(k + 1) * NB] : total;
    const int gb = k << shift;
    for (int i = threadIdx.x; i < fb; i += 256) fine[i] = 0;
    __syncthreads();
    for (int i = base + threadIdx.x; i < end; i += 256)
        atomicAdd(&fine[(int)(stg[i] >> 32) - gb], 1);
    __syncthreads();
    for (int i = threadIdx.x; i < fb; i += 256) {
        int g = gb + i;
        if (g < nbins) {
            int c = fine[i];
            cs[g] = c > 0 ? rsqrtf((float)c) : 0.f;
        }
    }
}

// ---------------- prescale: xs = bf16(x * cs0), [N_SRC0,128] ----------------
__global__ __launch_bounds__(256) void prescale_kernel(
        const float4* __restrict__ x4, const float* __restrict__ cs,
        uint2* __restrict__ xs) {
    int id = blockIdx.x * 256 + threadIdx.x;
    int row = id >> 5;
    float c = cs[row];
    float4 v = x4[id];
    uint2 o;
    o.x = packbf2(v.x * c, v.y * c);
    o.y = packbf2(v.z * c, v.w * c);
    xs[id] = o;
}

// ---------------- weight pack: Bp[kt][n][kk] = bf16(W[kt*32+kk][n]) ----------
__global__ void packW0_kernel(const float* __restrict__ W, unsigned short* __restrict__ Bp) {
    int id = blockIdx.x * 256 + threadIdx.x;       // 4*256*32 = 32768
    int kk = id & 31, n = (id >> 5) & 255, kt = id >> 13;
    Bp[id] = f2bf(W[(kt * 32 + kk) * 256 + n]);
}
__global__ void packW1_kernel(const float* __restrict__ W, unsigned short* __restrict__ Bp) {
    int id = blockIdx.x * 256 + threadIdx.x;       // 8*64*32 = 16384
    int kk = id & 31, n = (id >> 5) & 63, kt = id >> 11;
    Bp[id] = f2bf(W[(kt * 32 + kk) * 64 + n]);
}

// ---------------- layer-0 aggregation: 64 threads/row, bf16 gather ----------
__global__ __launch_bounds__(256) void agg0_kernel(
        const uint32_t* __restrict__ xs, const int* __restrict__ esrc,
        const int* __restrict__ off, uint32_t* __restrict__ aggb, int nrows) {
    int row = blockIdx.x * 4 + (threadIdx.x >> 6);
    int t = threadIdx.x & 63;
    if (row >= nrows) return;
    int b = off[row], e = off[row + 1];
    float a0 = 0.f, a1 = 0.f;
    int i = b;
    for (; i + 7 < e; i += 8) {
        int s0 = esrc[i],     s1 = esrc[i + 1], s2 = esrc[i + 2], s3 = esrc[i + 3];
        int s4 = esrc[i + 4], s5 = esrc[i + 5], s6 = esrc[i + 6], s7 = esrc[i + 7];
        uint32_t u0 = xs[(size_t)s0 * 64 + t];
        uint32_t u1 = xs[(size_t)s1 * 64 + t];
        uint32_t u2 = xs[(size_t)s2 * 64 + t];
        uint32_t u3 = xs[(size_t)s3 * 64 + t];
        uint32_t u4 = xs[(size_t)s4 * 64 + t];
        uint32_t u5 = xs[(size_t)s5 * 64 + t];
        uint32_t u6 = xs[(size_t)s6 * 64 + t];
        uint32_t u7 = xs[(size_t)s7 * 64 + t];
        a0 += ((bfu_lo(u0) + bfu_lo(u1)) + (bfu_lo(u2) + bfu_lo(u3)))
            + ((bfu_lo(u4) + bfu_lo(u5)) + (bfu_lo(u6) + bfu_lo(u7)));
        a1 += ((bfu_hi(u0) + bfu_hi(u1)) + (bfu_hi(u2) + bfu_hi(u3)))
            + ((bfu_hi(u4) + bfu_hi(u5)) + (bfu_hi(u6) + bfu_hi(u7)));
    }
    for (; i < e; ++i) {
        uint32_t u = xs[(size_t)esrc[i] * 64 + t];
        a0 += bfu_lo(u);
        a1 += bfu_hi(u);
    }
    float cd = (e > b) ? rsqrtf((float)(e - b)) : 0.f;
    aggb[(size_t)row * 64 + t] = packbf2(a0 * cd, a1 * cd);
}

// ---------------- GEMM0 (MFMA): h = relu(agg @ W0 + b0), bf16 out ----------
__global__ __launch_bounds__(256) void gemm0_mfma(
        const short* __restrict__ A,            // [N_DST0][128] bf16
        const short* __restrict__ Bp,           // [4][256][32] bf16
        const float* __restrict__ bias,         // [256]
        unsigned short* __restrict__ H) {       // [>=N_DST0][256] bf16
    const int w = threadIdx.x >> 6;
    const int l = threadIdx.x & 63;
    const int rbase = blockIdx.x * 32;
    const int cbase = w * 64;
    const int lr = l & 15;
    const int lk = (l >> 4) * 8;
    f32x4 acc[2][4] = {};
    #pragma unroll
    for (int kt = 0; kt < 4; ++kt) {
        short8 a[2], b[4];
        #pragma unroll
        for (int rt = 0; rt < 2; ++rt)
            a[rt] = *(const short8*)(A + (size_t)(rbase + rt * 16 + lr) * 128 + kt * 32 + lk);
        #pragma unroll
        for (int ct = 0; ct < 4; ++ct)
            b[ct] = *(const short8*)(Bp + (size_t)(kt * 256 + cbase + ct * 16 + lr) * 32 + lk);
        #pragma unroll
        for (int rt = 0; rt < 2; ++rt)
            #pragma unroll
            for (int ct = 0; ct < 4; ++ct)
                acc[rt][ct] = __builtin_amdgcn_mfma_f32_16x16x32_bf16(a[rt], b[ct], acc[rt][ct], 0, 0, 0);
    }
    const int orow0 = (l >> 4) * 4;
    #pragma unroll
    for (int rt = 0; rt < 2; ++rt) {
        #pragma unroll
        for (int ct = 0; ct < 4; ++ct) {
            int col = cbase + ct * 16 + lr;
            float bv = bias[col];
            #pragma unroll
            for (int j = 0; j < 4; ++j) {
                int row = rbase + rt * 16 + orow0 + j;
                float v = fmaxf(acc[rt][ct][j] + bv, 0.f);
                H[(size_t)row * 256 + col] = f2bf(v);
            }
        }
    }
}

// ---------------- GEMM-T (MFMA): y = (h0 @ W1) * cs1[row], bf16 out --------
__global__ __launch_bounds__(256) void gemmt_mfma(
        const short* __restrict__ A,            // [M_PAD][256] bf16
        const short* __restrict__ Bp,           // [8][64][32] bf16
        const float* __restrict__ cs1,          // [N_DST0]
        unsigned short* __restrict__ Y,         // [N_DST0][64] bf16
        int M) {
    const int w = threadIdx.x >> 6;
    const int l = threadIdx.x & 63;
    const int rbase = blockIdx.x * 128 + w * 32;
    const int lr = l & 15;
    const int lk = (l >> 4) * 8;
    f32x4 acc[2][4] = {};
    #pragma unroll
    for (int kt = 0; kt < 8; ++kt) {
        short8 a[2], b[4];
        #pragma unroll
        for (int rt = 0; rt < 2; ++rt)
            a[rt] = *(const short8*)(A + (size_t)(rbase + rt * 16 + lr) * 256 + kt * 32 + lk);
        #pragma unroll
        for (int ct = 0; ct < 4; ++ct)
            b[ct] = *(const short8*)(Bp + (size_t)(kt * 64 + ct * 16 + lr) * 32 + lk);
        #pragma unroll
        for (int rt = 0; rt < 2; ++rt)
            #pragma unroll
            for (int ct = 0; ct < 4; ++ct)
                acc[rt][ct] = __builtin_amdgcn_mfma_f32_16x16x32_bf16(a[rt], b[ct], acc[rt][ct], 0, 0, 0);
    }
    const int orow0 = (l >> 4) * 4;
    #pragma unroll
    for (int rt = 0; rt < 2; ++rt) {
        #pragma unroll
        for (int j = 0; j < 4; ++j) {
            int row = rbase + rt * 16 + orow0 + j;
            if (row < M) {
                float c = cs1[row];
                #pragma unroll
                for (int ct = 0; ct < 4; ++ct) {
                    int col = ct * 16 + lr;
                    Y[(size_t)row * 64 + col] = f2bf(acc[rt][ct][j] * c);
                }
            }
        }
    }
}

// ---------------- layer-1 aggregation: 32 threads/row, +bias, relu ---------
__global__ __launch_bounds__(256) void agg1_kernel(
        const uint32_t* __restrict__ y, const int* __restrict__ esrc,
        const int* __restrict__ off, const float* __restrict__ bias,
        float* __restrict__ out, int nrows) {
    int row = blockIdx.x * 8 + (threadIdx.x >> 5);
    int t = threadIdx.x & 31;
    if (row >= nrows) return;
    int b = off[row], e = off[row + 1];
    float a0 = 0.f, a1 = 0.f;
    int i = b;
    for (; i + 3 < e; i += 4) {
        int s0 = esrc[i], s1 = esrc[i + 1], s2 = esrc[i + 2], s3 = esrc[i + 3];
        uint32_t u0 = y[(size_t)s0 * 32 + t];
        uint32_t u1 = y[(size_t)s1 * 32 + t];
        uint32_t u2 = y[(size_t)s2 * 32 + t];
        uint32_t u3 = y[(size_t)s3 * 32 + t];
        a0 += (bfu_lo(u0) + bfu_lo(u1)) + (bfu_lo(u2) + bfu_lo(u3));
        a1 += (bfu_hi(u0) + bfu_hi(u1)) + (bfu_hi(u2) + bfu_hi(u3));
    }
    for (; i < e; ++i) {
        uint32_t u = y[(size_t)esrc[i] * 32 + t];
        a0 += bfu_lo(u);
        a1 += bfu_hi(u);
    }
    float cd = (e > b) ? rsqrtf((float)(e - b)) : 0.f;
    float2 o;
    o.x = fmaxf(a0 * cd + bias[t * 2], 0.f);
    o.y = fmaxf(a1 * cd + bias[t * 2 + 1], 0.f);
    *(float2*)(out + (size_t)row * 64 + t * 2) = o;
}

extern "C" void kernel_launch(void* const* d_in, const int* in_sizes, int n_in,
                              void* d_out, int out_size, void* d_ws, size_t ws_size,
                              hipStream_t stream) {
    const float* x    = (const float*)d_in[0];
    const int*   src0 = (const int*)d_in[1];
    const int*   dst0 = (const int*)d_in[2];
    const int*   src1 = (const int*)d_in[3];
    const int*   dst1 = (const int*)d_in[4];
    const float* W0   = (const float*)d_in[5];
    const float* b0   = (const float*)d_in[6];
    const float* W1   = (const float*)d_in[7];
    const float* b1   = (const float*)d_in[8];
    float* out = (float*)d_out;

    const int E0 = in_sizes[1];
    const int E1 = in_sizes[3];
    const int M_PAD = 100096;   // 782 * 128

    // staging region totals (absolute offsets into concatenated stg)
    const int T_D0 = E0;
    const int T_S0 = 2 * E0;
    const int T_D1 = 2 * E0 + E1;
    const int T_S1 = 2 * E0 + 2 * E1;

    char* p = (char*)d_ws;
    auto alloc = [&](size_t bytes) {
        char* r = p;
        p += (bytes + 511) & ~(size_t)511;
        return r;
    };
    int*   bh    = (int*)alloc((size_t)BH_TOT * 4);          // 4.3 MB
    int*   sums  = (int*)alloc(1024 * 4);
    int*   off0  = (int*)alloc((size_t)(N_DST0 + 1) * 4);
    int*   off1  = (int*)alloc((size_t)(N_DST1 + 1) * 4);
    float* cs0   = (float*)alloc((size_t)N_SRC0 * 4);
    float* cs1   = (float*)alloc((size_t)N_DST0 * 4);
    int*   esrc0 = (int*)alloc((size_t)E0 * 4);
    int*   esrc1 = (int*)alloc((size_t)E1 * 4);
    unsigned short* W0p = (unsigned short*)alloc((size_t)32768 * 2);
    unsigned short* W1p = (unsigned short*)alloc((size_t)16384 * 2);
    // big region: stg (u64[T_S1], 64MB) aliased with {xs/h0b (102.4MB) | aggb/y1b (25.6MB)}
    size_t bigA = (size_t)N_SRC0 * 128 * 2;                  // xs / h0b
    size_t bigB = (size_t)N_DST0 * 128 * 2;                  // aggb / y1b
    size_t bigStg = (size_t)T_S1 * 8;
    size_t bigSz = bigA + bigB;
    if (bigStg > bigSz) bigSz = bigStg;
    char* big = alloc(bigSz);

    uint64_t* stg = (uint64_t*)big;                          // dead before prescale
    uint32_t* xs   = (uint32_t*)big;
    unsigned short* h0b = (unsigned short*)big;
    uint32_t* aggb = (uint32_t*)(big + bigA);
    unsigned short* y1b = (unsigned short*)(big + bigA);

    int* bh_d0 = bh + BH_D0;
    int* bh_s0 = bh + BH_S0;
    int* bh_d1 = bh + BH_D1;
    int* bh_s1 = bh + BH_S1;

    // --- pass 1: coarse per-block histograms (no global atomics anywhere) ---
    part_hist2<<<NB0, 256, (NK_D0 + NK_S0) * 4, stream>>>(
        src0, dst0, E0, SH_S0, NK_S0, SH_D0, NK_D0, NB0, bh_d0, bh_s0);
    part_hist2<<<NB1, 256, (NK_D1 + NK_S1) * 4, stream>>>(
        src1, dst1, E1, SH_S1, NK_S1, SH_D1, NK_D1, NB1, bh_d1, bh_s1);

    // --- global exclusive scan over all four tables ---
    const int nsb = (BH_TOT + SCAN_TILE - 1) / SCAN_TILE;    // 526
    scan1_kernel<<<nsb, 256, 0, stream>>>(bh, bh, sums, BH_TOT);
    scan2_kernel<<<1, 256, 0, stream>>>(sums, nsb);
    scan3_kernel<<<(BH_TOT + 255) / 256, 256, 0, stream>>>(bh, sums, BH_TOT);

    // --- pass 2: scatter edges into bucket-major staging ---
    part_scat2<<<NB0, 256, (NK_D0 + NK_S0) * 4, stream>>>(
        src0, dst0, E0, SH_S0, NK_S0, SH_D0, NK_D0, NB0, bh_d0, bh_s0, stg);
    part_scat2<<<NB1, 256, (NK_D1 + NK_S1) * 4, stream>>>(
        src1, dst1, E1, SH_S1, NK_S1, SH_D1, NK_D1, NB1, bh_d1, bh_s1, stg);

    // --- pass 3: per-bucket fine CSR / degree ---
    fine_csr<<<NK_D0, 256, 0, stream>>>(stg, bh_d0, NB0, SH_D0, N_DST0, T_D0, 0, off0, esrc0);
    fine_hist<<<NK_S0, 256, 0, stream>>>(stg, bh_s0, NB0, SH_S0, N_SRC0, T_S0, cs0);
    fine_csr<<<NK_D1, 256, 0, stream>>>(stg, bh_d1, NB1, SH_D1, N_DST1, T_D1, 2 * E0, off1, esrc1);
    fine_hist<<<NK_S1, 256, 0, stream>>>(stg, bh_s1, NB1, SH_S1, N_DST0, T_S1, cs1);

    // --- weight packs ---
    packW0_kernel<<<128, 256, 0, stream>>>(W0, W0p);
    packW1_kernel<<<64, 256, 0, stream>>>(W1, W1p);

    // --- prescale x -> bf16 (stg fully consumed; big region repurposed) ---
    prescale_kernel<<<N_SRC0 * 32 / 256, 256, 0, stream>>>((const float4*)x, cs0, (uint2*)xs);

    // layer 0
    agg0_kernel<<<N_DST0 / 4, 256, 0, stream>>>(xs, esrc0, off0, aggb, N_DST0);
    gemm0_mfma<<<N_DST0 / 32, 256, 0, stream>>>((const short*)aggb, (const short*)W0p, b0, h0b);

    // layer 1
    gemmt_mfma<<<M_PAD / 128, 256, 0, stream>>>((const short*)h0b, (const short*)W1p, cs1, y1b, N_DST0);
    agg1_kernel<<<N_DST1 / 8, 256, 0, stream>>>((const uint32_t*)y1b, esrc1, off1, b1, out, N_DST1);
}

// Round 6
// 436.575 us; speedup vs baseline: 19.7183x; 1.0712x over previous
//
#include <hip/hip_runtime.h>
#include <hip/hip_bf16.h>
#include <hip/hip_fp16.h>
#include <stdint.h>

#define N_SRC0 400000
#define N_DST0 100000
#define N_DST1 25000

// coarse-bucket geometry (node counts are fixed)
#define SH_D0 9
#define NK_D0 196      // ceil(100000/512)
#define SH_S0 9
#define NK_S0 782      // ceil(400000/512)
#define SH_D1 8
#define NK_D1 98       // ceil(25000/256)
#define SH_S1 9
#define NK_S1 196      // ceil(100000/512)
#define NB0 1024
#define NB1 256

// bh concatenated layout offsets (scan order == staging order)
#define BH_D0 0
#define BH_S0 (NK_D0 * NB0)
#define BH_D1 (BH_S0 + NK_S0 * NB0)
#define BH_S1 (BH_D1 + NK_D1 * NB1)
#define BH_TOT (BH_S1 + NK_S1 * NB1)

typedef __attribute__((ext_vector_type(8))) short short8;
typedef __attribute__((ext_vector_type(4))) float f32x4;

__device__ __forceinline__ unsigned short f2bf(float f) {
    __hip_bfloat16 h = __float2bfloat16(f);
    union { __hip_bfloat16 h; unsigned short u; } c;
    c.h = h;
    return c.u;
}
__device__ __forceinline__ uint32_t packbf2(float a, float b) {
    return (uint32_t)f2bf(a) | ((uint32_t)f2bf(b) << 16);
}
__device__ __forceinline__ __half2 u2h2(uint32_t u) {
    return __builtin_bit_cast(__half2, u);
}

// ============ pass 1: per-block coarse histograms (src & dst fused) ============
__device__ __forceinline__ void hist_body(
        const int* __restrict__ src, const int* __restrict__ dst, int n,
        int sshift, int snb, int dshift, int dnb, int NB, int blk,
        int* __restrict__ bhd, int* __restrict__ bhs, int* h) {
    for (int i = threadIdx.x; i < dnb + snb; i += 256) h[i] = 0;
    __syncthreads();
    const int per = (n + NB - 1) / NB;
    const int b = blk * per;
    const int e = min(b + per, n);
    for (int i = b + threadIdx.x; i < e; i += 256) {
        atomicAdd(&h[dst[i] >> dshift], 1);
        atomicAdd(&h[dnb + (src[i] >> sshift)], 1);
    }
    __syncthreads();
    for (int i = threadIdx.x; i < dnb; i += 256) bhd[(size_t)i * NB + blk] = h[i];
    for (int i = threadIdx.x; i < snb; i += 256) bhs[(size_t)i * NB + blk] = h[dnb + i];
}

__global__ __launch_bounds__(256) void hist_fused(
        const int* __restrict__ src0, const int* __restrict__ dst0, int E0,
        const int* __restrict__ src1, const int* __restrict__ dst1, int E1,
        int* __restrict__ bh) {
    extern __shared__ int h[];
    if (blockIdx.x < NB0)
        hist_body(src0, dst0, E0, SH_S0, NK_S0, SH_D0, NK_D0, NB0, blockIdx.x,
                  bh + BH_D0, bh + BH_S0, h);
    else
        hist_body(src1, dst1, E1, SH_S1, NK_S1, SH_D1, NK_D1, NB1, blockIdx.x - NB0,
                  bh + BH_D1, bh + BH_S1, h);
}

// ============ global exclusive scan over bh ============
#define SCAN_ITEMS 8
#define SCAN_TILE 2048

__global__ __launch_bounds__(256) void scan1_kernel(
        const int* __restrict__ in, int* __restrict__ out,
        int* __restrict__ sums, int n) {
    __shared__ int lds[256];
    const int tid = threadIdx.x;
    const int base = blockIdx.x * SCAN_TILE + tid * SCAN_ITEMS;
    int v[SCAN_ITEMS];
    int run = 0;
    #pragma unroll
    for (int i = 0; i < SCAN_ITEMS; ++i) {
        int t = (base + i < n) ? in[base + i] : 0;
        v[i] = run;
        run += t;
    }
    lds[tid] = run;
    __syncthreads();
    int incl = run;
    for (int off = 1; off < 256; off <<= 1) {
        int u = (tid >= off) ? lds[tid - off] : 0;
        __syncthreads();
        incl += u;
        lds[tid] = incl;
        __syncthreads();
    }
    if (tid == 255) sums[blockIdx.x] = incl;
    int excl = incl - run;
    #pragma unroll
    for (int i = 0; i < SCAN_ITEMS; ++i)
        if (base + i < n) out[base + i] = excl + v[i];
}

__global__ __launch_bounds__(256) void scan2_kernel(int* __restrict__ sums, int nb) {
    __shared__ int lds[256];
    const int tid = threadIdx.x;
    const int base = tid * 4;
    int v[4];
    int run = 0;
    #pragma unroll
    for (int i = 0; i < 4; ++i) {
        int t = (base + i < nb) ? sums[base + i] : 0;
        v[i] = run;
        run += t;
    }
    lds[tid] = run;
    __syncthreads();
    int incl = run;
    for (int off = 1; off < 256; off <<= 1) {
        int u = (tid >= off) ? lds[tid - off] : 0;
        __syncthreads();
        incl += u;
        lds[tid] = incl;
        __syncthreads();
    }
    int excl = incl - run;
    #pragma unroll
    for (int i = 0; i < 4; ++i)
        if (base + i < nb) sums[base + i] = excl + v[i];
}

__global__ void scan3_kernel(int* __restrict__ out, const int* __restrict__ sums, int n) {
    int i = blockIdx.x * blockDim.x + threadIdx.x;
    if (i < n) out[i] += sums[i / SCAN_TILE];
}

// ============ pass 2: scatter to bucket-major u32 staging ============
// dst-keyed entry: (d_local << ksh) | s ; src-keyed entry: s
__device__ __forceinline__ void scat_body(
        const int* __restrict__ src, const int* __restrict__ dst, int n,
        int sshift, int snb, int dshift, int dnb, int NB, int blk, int ksh,
        const int* __restrict__ bhd, const int* __restrict__ bhs,
        uint32_t* __restrict__ stg, int* cur) {
    for (int i = threadIdx.x; i < dnb; i += 256) cur[i] = bhd[(size_t)i * NB + blk];
    for (int i = threadIdx.x; i < snb; i += 256) cur[dnb + i] = bhs[(size_t)i * NB + blk];
    __syncthreads();
    const int per = (n + NB - 1) / NB;
    const int b = blk * per;
    const int e = min(b + per, n);
    const int dmask = (1 << dshift) - 1;
    for (int i = b + threadIdx.x; i < e; i += 256) {
        int s = src[i], d = dst[i];
        int pd = atomicAdd(&cur[d >> dshift], 1);
        stg[pd] = ((uint32_t)(d & dmask) << ksh) | (uint32_t)s;
        int ps = atomicAdd(&cur[dnb + (s >> sshift)], 1);
        stg[ps] = (uint32_t)s;
    }
}

__global__ __launch_bounds__(256) void scat_fused(
        const int* __restrict__ src0, const int* __restrict__ dst0, int E0,
        const int* __restrict__ src1, const int* __restrict__ dst1, int E1,
        const int* __restrict__ bh, uint32_t* __restrict__ stg) {
    extern __shared__ int cur[];
    if (blockIdx.x < NB0)
        scat_body(src0, dst0, E0, SH_S0, NK_S0, SH_D0, NK_D0, NB0, blockIdx.x, 19,
                  bh + BH_D0, bh + BH_S0, stg, cur);
    else
        scat_body(src1, dst1, E1, SH_S1, NK_S1, SH_D1, NK_D1, NB1, blockIdx.x - NB0, 17,
                  bh + BH_D1, bh + BH_S1, stg, cur);
}

// ============ pass 3: per-bucket fine CSR / degree (fused 4 roles) ============
__device__ __forceinline__ void fine_csr_body(
        const uint32_t* __restrict__ stg, const int* __restrict__ bht,
        int NB, int shift, int ksh, int nbins, int total, int rel, int nbkt, int k,
        int* __restrict__ off, int* __restrict__ esrc, int* fine, int* part) {
    const int fb = 1 << shift;
    const int base = bht[(size_t)k * NB];
    const int end = (k + 1 < nbkt) ? bht[(size_t)(k + 1) * NB] : total;
    const int gb = k << shift;
    const int t = threadIdx.x;
    const uint32_t mask = (1u << ksh) - 1;
    for (int i = t; i < fb; i += 256) fine[i] = 0;
    __syncthreads();
    for (int i = base + t; i < end; i += 256)
        atomicAdd(&fine[stg[i] >> ksh], 1);
    __syncthreads();
    int a0 = (2 * t < fb) ? fine[2 * t] : 0;
    int a1 = (2 * t + 1 < fb) ? fine[2 * t + 1] : 0;
    part[t] = a0 + a1;
    __syncthreads();
    int incl = part[t];
    for (int o = 1; o < 256; o <<= 1) {
        int u = (t >= o) ? part[t - o] : 0;
        __syncthreads();
        incl += u;
        part[t] = incl;
        __syncthreads();
    }
    int excl = incl - (a0 + a1);
    if (2 * t < fb) fine[2 * t] = excl;
    if (2 * t + 1 < fb) fine[2 * t + 1] = excl + a0;
    __syncthreads();
    const int rb = base - rel;
    for (int i = t; i < fb; i += 256) {
        int g = gb + i;
        if (g < nbins) off[g] = rb + fine[i];
    }
    if (k == nbkt - 1 && t == 0) off[nbins] = total - rel;
    __syncthreads();
    for (int i = base + t; i < end; i += 256) {
        uint32_t v = stg[i];
        int p = atomicAdd(&fine[v >> ksh], 1);
        esrc[rb + p] = (int)(v & mask);
    }
}

__device__ __forceinline__ void fine_deg_body(
        const uint32_t* __restrict__ stg, const int* __restrict__ bht,
        int NB, int shift, int nbins, int total, int nbkt, int k,
        uint32_t* __restrict__ csp, float* __restrict__ csf, int* fine) {
    const int fb = 1 << shift;
    const int base = bht[(size_t)k * NB];
    const int end = (k + 1 < nbkt) ? bht[(size_t)(k + 1) * NB] : total;
    const int gb = k << shift;
    for (int i = threadIdx.x; i < fb; i += 256) fine[i] = 0;
    __syncthreads();
    for (int i = base + threadIdx.x; i < end; i += 256)
        atomicAdd(&fine[(int)stg[i] - gb], 1);
    __syncthreads();
    for (int i = threadIdx.x; i < fb; i += 256) {
        int g = gb + i;
        if (g < nbins) {
            int c = fine[i];
            float r = c > 0 ? rsqrtf((float)c) : 0.f;
            if (csp) {
                __half2 h = __floats2half2_rn(r, r);
                csp[g] = __builtin_bit_cast(uint32_t, h);
            } else {
                csf[g] = r;
            }
        }
    }
}

__global__ __launch_bounds__(256) void fine_fused(
        const uint32_t* __restrict__ stg, const int* __restrict__ bh,
        int E0, int E1,
        int* __restrict__ off0, int* __restrict__ esrc0,
        int* __restrict__ off1, int* __restrict__ esrc1,
        uint32_t* __restrict__ cs0p, float* __restrict__ cs1) {
    __shared__ int fine[512];
    __shared__ int part[256];
    int kb = blockIdx.x;
    if (kb < NK_D0) {
        fine_csr_body(stg, bh + BH_D0, NB0, SH_D0, 19, N_DST0, E0, 0, NK_D0, kb,
                      off0, esrc0, fine, part);
        return;
    }
    kb -= NK_D0;
    if (kb < NK_S0) {
        fine_deg_body(stg, bh + BH_S0, NB0, SH_S0, N_SRC0, 2 * E0, NK_S0, kb,
                      cs0p, nullptr, fine);
        return;
    }
    kb -= NK_S0;
    if (kb < NK_D1) {
        fine_csr_body(stg, bh + BH_D1, NB1, SH_D1, 17, N_DST1, 2 * E0 + E1, 2 * E0, NK_D1, kb,
                      off1, esrc1, fine, part);
        return;
    }
    kb -= NK_D1;
    fine_deg_body(stg, bh + BH_S1, NB1, SH_S1, N_DST0, 2 * E0 + 2 * E1, NK_S1, kb,
                  nullptr, cs1, fine);
}

// ---------------- xconv: xs = f16(x), [N_SRC0,128] (no cs dependency) --------
__global__ __launch_bounds__(256) void xconv_kernel(
        const float4* __restrict__ x4, uint2* __restrict__ xs) {
    int id = blockIdx.x * 256 + threadIdx.x;
    float4 v = x4[id];
    uint2 o;
    o.x = __builtin_bit_cast(uint32_t, __floats2half2_rn(v.x, v.y));
    o.y = __builtin_bit_cast(uint32_t, __floats2half2_rn(v.z, v.w));
    xs[id] = o;
}

// ---------------- weight packs (fused) ----------------
__global__ __launch_bounds__(256) void packw_fused(
        const float* __restrict__ W0, const float* __restrict__ W1,
        unsigned short* __restrict__ W0p, unsigned short* __restrict__ W1p) {
    int blk = blockIdx.x;
    if (blk < 128) {
        int id = blk * 256 + threadIdx.x;
        int kk = id & 31, n2 = (id >> 5) & 255, kt = id >> 13;
        W0p[id] = f2bf(W0[(kt * 32 + kk) * 256 + n2]);
    } else {
        int id = (blk - 128) * 256 + threadIdx.x;
        int kk = id & 31, n2 = (id >> 5) & 63, kt = id >> 11;
        W1p[id] = f2bf(W1[(kt * 32 + kk) * 64 + n2]);
    }
}

// ---------------- layer-0 aggregation: 16 lanes/row, uint4 f16 gather, pk_fma ----
__global__ __launch_bounds__(256) void agg0_kernel(
        const uint4* __restrict__ xs4, const int* __restrict__ esrc,
        const int* __restrict__ off, const uint32_t* __restrict__ cs0p,
        uint4* __restrict__ aggb4) {
    const int row = blockIdx.x * 16 + (threadIdx.x >> 4);
    const int t = threadIdx.x & 15;
    const int b = off[row], e = off[row + 1];
    const __half2 z = __builtin_bit_cast(__half2, 0u);
    __half2 aA0 = z, aA1 = z, aA2 = z, aA3 = z;
    __half2 aB0 = z, aB1 = z, aB2 = z, aB3 = z;
    int i = b;
    for (; i + 8 <= e; i += 8) {
        #pragma unroll
        for (int k = 0; k < 8; k += 2) {
            int s0 = esrc[i + k], s1 = esrc[i + k + 1];
            __half2 c0 = u2h2(cs0p[s0]), c1 = u2h2(cs0p[s1]);
            uint4 v0 = xs4[(size_t)s0 * 16 + t];
            uint4 v1 = xs4[(size_t)s1 * 16 + t];
            aA0 = __hfma2(u2h2(v0.x), c0, aA0);
            aA1 = __hfma2(u2h2(v0.y), c0, aA1);
            aA2 = __hfma2(u2h2(v0.z), c0, aA2);
            aA3 = __hfma2(u2h2(v0.w), c0, aA3);
            aB0 = __hfma2(u2h2(v1.x), c1, aB0);
            aB1 = __hfma2(u2h2(v1.y), c1, aB1);
            aB2 = __hfma2(u2h2(v1.z), c1, aB2);
            aB3 = __hfma2(u2h2(v1.w), c1, aB3);
        }
    }
    for (; i < e; ++i) {
        int s = esrc[i];
        __half2 c = u2h2(cs0p[s]);
        uint4 v = xs4[(size_t)s * 16 + t];
        aA0 = __hfma2(u2h2(v.x), c, aA0);
        aA1 = __hfma2(u2h2(v.y), c, aA1);
        aA2 = __hfma2(u2h2(v.z), c, aA2);
        aA3 = __hfma2(u2h2(v.w), c, aA3);
    }
    float cd = (e > b) ? rsqrtf((float)(e - b)) : 0.f;
    __half2 s0 = __hadd2(aA0, aB0), s1 = __hadd2(aA1, aB1);
    __half2 s2 = __hadd2(aA2, aB2), s3 = __hadd2(aA3, aB3);
    uint4 o;
    o.x = packbf2(__low2float(s0) * cd, __high2float(s0) * cd);
    o.y = packbf2(__low2float(s1) * cd, __high2float(s1) * cd);
    o.z = packbf2(__low2float(s2) * cd, __high2float(s2) * cd);
    o.w = packbf2(__low2float(s3) * cd, __high2float(s3) * cd);
    aggb4[(size_t)row * 16 + t] = o;
}

// ---------------- GEMM0 (MFMA): h = relu(agg @ W0 + b0), bf16 out ----------
__global__ __launch_bounds__(256) void gemm0_mfma(
        const short* __restrict__ A,            // [N_DST0][128] bf16
        const short* __restrict__ Bp,           // [4][256][32] bf16
        const float* __restrict__ bias,         // [256]
        unsigned short* __restrict__ H) {       // [>=N_DST0][256] bf16
    const int w = threadIdx.x >> 6;
    const int l = threadIdx.x & 63;
    const int rbase = blockIdx.x * 32;
    const int cbase = w * 64;
    const int lr = l & 15;
    const int lk = (l >> 4) * 8;
    f32x4 acc[2][4] = {};
    #pragma unroll
    for (int kt = 0; kt < 4; ++kt) {
        short8 a[2], b[4];
        #pragma unroll
        for (int rt = 0; rt < 2; ++rt)
            a[rt] = *(const short8*)(A + (size_t)(rbase + rt * 16 + lr) * 128 + kt * 32 + lk);
        #pragma unroll
        for (int ct = 0; ct < 4; ++ct)
            b[ct] = *(const short8*)(Bp + (size_t)(kt * 256 + cbase + ct * 16 + lr) * 32 + lk);
        #pragma unroll
        for (int rt = 0; rt < 2; ++rt)
            #pragma unroll
            for (int ct = 0; ct < 4; ++ct)
                acc[rt][ct] = __builtin_amdgcn_mfma_f32_16x16x32_bf16(a[rt], b[ct], acc[rt][ct], 0, 0, 0);
    }
    const int orow0 = (l >> 4) * 4;
    #pragma unroll
    for (int rt = 0; rt < 2; ++rt) {
        #pragma unroll
        for (int ct = 0; ct < 4; ++ct) {
            int col = cbase + ct * 16 + lr;
            float bv = bias[col];
            #pragma unroll
            for (int j = 0; j < 4; ++j) {
                int row = rbase + rt * 16 + orow0 + j;
                float v = fmaxf(acc[rt][ct][j] + bv, 0.f);
                H[(size_t)row * 256 + col] = f2bf(v);
            }
        }
    }
}

// ---------------- GEMM-T (MFMA): y = (h0 @ W1) * cs1[row], f16 out --------
__global__ __launch_bounds__(256) void gemmt_mfma(
        const short* __restrict__ A,            // [M_PAD][256] bf16
        const short* __restrict__ Bp,           // [8][64][32] bf16
        const float* __restrict__ cs1,          // [N_DST0]
        __half* __restrict__ Y,                 // [N_DST0][64] f16
        int M) {
    const int w = threadIdx.x >> 6;
    const int l = threadIdx.x & 63;
    const int rbase = blockIdx.x * 128 + w * 32;
    const int lr = l & 15;
    const int lk = (l >> 4) * 8;
    f32x4 acc[2][4] = {};
    #pragma unroll
    for (int kt = 0; kt < 8; ++kt) {
        short8 a[2], b[4];
        #pragma unroll
        for (int rt = 0; rt < 2; ++rt)
            a[rt] = *(const short8*)(A + (size_t)(rbase + rt * 16 + lr) * 256 + kt * 32 + lk);
        #pragma unroll
        for (int ct = 0; ct < 4; ++ct)
            b[ct] = *(const short8*)(Bp + (size_t)(kt * 64 + ct * 16 + lr) * 32 + lk);
        #pragma unroll
        for (int rt = 0; rt < 2; ++rt)
            #pragma unroll
            for (int ct = 0; ct < 4; ++ct)
                acc[rt][ct] = __builtin_amdgcn_mfma_f32_16x16x32_bf16(a[rt], b[ct], acc[rt][ct], 0, 0, 0);
    }
    const int orow0 = (l >> 4) * 4;
    #pragma unroll
    for (int rt = 0; rt < 2; ++rt) {
        #pragma unroll
        for (int j = 0; j < 4; ++j) {
            int row = rbase + rt * 16 + orow0 + j;
            if (row < M) {
                float c = cs1[row];
                #pragma unroll
                for (int ct = 0; ct < 4; ++ct) {
                    int col = ct * 16 + lr;
                    Y[(size_t)row * 64 + col] = __float2half(acc[rt][ct][j] * c);
                }
            }
        }
    }
}

// ---------------- layer-1 aggregation: 16 lanes/row, uint2 f16 gather ------
__global__ __launch_bounds__(256) void agg1_kernel(
        const uint2* __restrict__ y2, const int* __restrict__ esrc,
        const int* __restrict__ off, const float* __restrict__ bias,
        float* __restrict__ out, int nrows) {
    int row = blockIdx.x * 16 + (threadIdx.x >> 4);
    int t = threadIdx.x & 15;
    if (row >= nrows) return;
    int b = off[row], e = off[row + 1];
    const __half2 z = __builtin_bit_cast(__half2, 0u);
    __half2 aA0 = z, aA1 = z, aB0 = z, aB1 = z;
    int i = b;
    for (; i + 8 <= e; i += 8) {
        #pragma unroll
        for (int k = 0; k < 8; k += 2) {
            int s0 = esrc[i + k], s1 = esrc[i + k + 1];
            uint2 v0 = y2[(size_t)s0 * 16 + t];
            uint2 v1 = y2[(size_t)s1 * 16 + t];
            aA0 = __hadd2(aA0, u2h2(v0.x));
            aA1 = __hadd2(aA1, u2h2(v0.y));
            aB0 = __hadd2(aB0, u2h2(v1.x));
            aB1 = __hadd2(aB1, u2h2(v1.y));
        }
    }
    for (; i < e; ++i) {
        uint2 v = y2[(size_t)esrc[i] * 16 + t];
        aA0 = __hadd2(aA0, u2h2(v.x));
        aA1 = __hadd2(aA1, u2h2(v.y));
    }
    float cd = (e > b) ? rsqrtf((float)(e - b)) : 0.f;
    __half2 s0 = __hadd2(aA0, aB0), s1 = __hadd2(aA1, aB1);
    float4 bv = *(const float4*)(bias + t * 4);
    float4 o;
    o.x = fmaxf(__low2float(s0) * cd + bv.x, 0.f);
    o.y = fmaxf(__high2float(s0) * cd + bv.y, 0.f);
    o.z = fmaxf(__low2float(s1) * cd + bv.z, 0.f);
    o.w = fmaxf(__high2float(s1) * cd + bv.w, 0.f);
    *(float4*)(out + (size_t)row * 64 + t * 4) = o;
}

extern "C" void kernel_launch(void* const* d_in, const int* in_sizes, int n_in,
                              void* d_out, int out_size, void* d_ws, size_t ws_size,
                              hipStream_t stream) {
    const float* x    = (const float*)d_in[0];
    const int*   src0 = (const int*)d_in[1];
    const int*   dst0 = (const int*)d_in[2];
    const int*   src1 = (const int*)d_in[3];
    const int*   dst1 = (const int*)d_in[4];
    const float* W0   = (const float*)d_in[5];
    const float* b0   = (const float*)d_in[6];
    const float* W1   = (const float*)d_in[7];
    const float* b1   = (const float*)d_in[8];
    float* out = (float*)d_out;

    const int E0 = in_sizes[1];
    const int E1 = in_sizes[3];
    const int M_PAD = 100096;   // 782 * 128

    char* p = (char*)d_ws;
    auto alloc = [&](size_t bytes) {
        char* r = p;
        p += (bytes + 511) & ~(size_t)511;
        return r;
    };
    int*      bh    = (int*)alloc((size_t)BH_TOT * 4);
    int*      sums  = (int*)alloc(1024 * 4);
    int*      off0  = (int*)alloc((size_t)(N_DST0 + 1) * 4);
    int*      off1  = (int*)alloc((size_t)(N_DST1 + 1) * 4);
    uint32_t* cs0p  = (uint32_t*)alloc((size_t)N_SRC0 * 4);
    float*    cs1   = (float*)alloc((size_t)N_DST0 * 4);
    int*      esrc0 = (int*)alloc((size_t)E0 * 4);
    int*      esrc1 = (int*)alloc((size_t)E1 * 4);
    unsigned short* W0p = (unsigned short*)alloc((size_t)32768 * 2);
    unsigned short* W1p = (unsigned short*)alloc((size_t)16384 * 2);
    // big region: stg (u32[2E0+2E1] = 32MB) dead before xconv; then xs/h0b + aggb/y1b
    size_t bigA = (size_t)N_SRC0 * 128 * 2;   // xs (f16) / h0b (bf16)
    size_t bigB = (size_t)N_DST0 * 128 * 2;   // aggb (bf16) / y1b (f16)
    size_t bigStg = (size_t)(2 * E0 + 2 * E1) * 4;
    size_t bigSz = bigA + bigB;
    if (bigStg > bigSz) bigSz = bigStg;
    char* big = alloc(bigSz);

    uint32_t* stg = (uint32_t*)big;
    uint2*    xs  = (uint2*)big;
    unsigned short* h0b = (unsigned short*)big;
    char* regB = big + bigA;
    uint4* aggb4 = (uint4*)regB;
    __half* y1b  = (__half*)regB;

    // --- CSR build: hist -> scan -> scatter -> fine (no global atomics) ---
    hist_fused<<<NB0 + NB1, 256, (NK_D0 + NK_S0) * 4, stream>>>(
        src0, dst0, E0, src1, dst1, E1, bh);
    const int nsb = (BH_TOT + SCAN_TILE - 1) / SCAN_TILE;   // 526
    scan1_kernel<<<nsb, 256, 0, stream>>>(bh, bh, sums, BH_TOT);
    scan2_kernel<<<1, 256, 0, stream>>>(sums, nsb);
    scan3_kernel<<<(BH_TOT + 255) / 256, 256, 0, stream>>>(bh, sums, BH_TOT);
    scat_fused<<<NB0 + NB1, 256, (NK_D0 + NK_S0) * 4, stream>>>(
        src0, dst0, E0, src1, dst1, E1, bh, stg);
    fine_fused<<<NK_D0 + NK_S0 + NK_D1 + NK_S1, 256, 0, stream>>>(
        stg, bh, E0, E1, off0, esrc0, off1, esrc1, cs0p, cs1);

    // --- weight packs + x -> f16 (stg fully consumed; big region repurposed) ---
    packw_fused<<<192, 256, 0, stream>>>(W0, W1, W0p, W1p);
    xconv_kernel<<<N_SRC0 * 32 / 256, 256, 0, stream>>>((const float4*)x, xs);

    // layer 0
    agg0_kernel<<<N_DST0 / 16, 256, 0, stream>>>(
        (const uint4*)xs, esrc0, off0, cs0p, aggb4);
    gemm0_mfma<<<N_DST0 / 32, 256, 0, stream>>>(
        (const short*)aggb4, (const short*)W0p, b0, h0b);

    // layer 1
    gemmt_mfma<<<M_PAD / 128, 256, 0, stream>>>(
        (const short*)h0b, (const short*)W1p, cs1, y1b, N_DST0);
    agg1_kernel<<<(N_DST1 + 15) / 16, 256, 0, stream>>>(
        (const uint2*)y1b, esrc1, off1, b1, out, N_DST1);
}

// Round 7
// 397.643 us; speedup vs baseline: 21.6488x; 1.0979x over previous
//
#include <hip/hip_runtime.h>
#include <hip/hip_bf16.h>
#include <hip/hip_fp16.h>
#include <stdint.h>

#define N_SRC0 400000
#define N_DST0 100000
#define N_DST1 25000

// coarse-bucket geometry (node counts are fixed)
#define SH_D0 9
#define NK_D0 196      // ceil(100000/512)
#define SH_S0 9
#define NK_S0 782      // ceil(400000/512)
#define SH_D1 8
#define NK_D1 98       // ceil(25000/256)
#define SH_S1 9
#define NK_S1 196      // ceil(100000/512)
#define NB0 1024
#define NB1 256

// bh concatenated layout offsets (scan order == staging order)
#define BH_D0 0
#define BH_S0 (NK_D0 * NB0)
#define BH_D1 (BH_S0 + NK_S0 * NB0)
#define BH_S1 (BH_D1 + NK_D1 * NB1)
#define BH_TOT (BH_S1 + NK_S1 * NB1)

typedef __attribute__((ext_vector_type(8))) short short8;
typedef __attribute__((ext_vector_type(4))) float f32x4;

__device__ __forceinline__ unsigned short f2bf(float f) {
    __hip_bfloat16 h = __float2bfloat16(f);
    union { __hip_bfloat16 h; unsigned short u; } c;
    c.h = h;
    return c.u;
}
__device__ __forceinline__ uint32_t packbf2(float a, float b) {
    return (uint32_t)f2bf(a) | ((uint32_t)f2bf(b) << 16);
}
__device__ __forceinline__ __half2 u2h2(uint32_t u) {
    return __builtin_bit_cast(__half2, u);
}

// ============ pass 1: per-block coarse histograms (src & dst fused) ============
__device__ __forceinline__ void hist_body(
        const int* __restrict__ src, const int* __restrict__ dst, int n,
        int sshift, int snb, int dshift, int dnb, int NB, int blk,
        int* __restrict__ bhd, int* __restrict__ bhs, int* h) {
    for (int i = threadIdx.x; i < dnb + snb; i += 256) h[i] = 0;
    __syncthreads();
    const int per = (n + NB - 1) / NB;
    const int b = blk * per;
    const int e = min(b + per, n);
    for (int i = b + threadIdx.x; i < e; i += 256) {
        atomicAdd(&h[dst[i] >> dshift], 1);
        atomicAdd(&h[dnb + (src[i] >> sshift)], 1);
    }
    __syncthreads();
    for (int i = threadIdx.x; i < dnb; i += 256) bhd[(size_t)i * NB + blk] = h[i];
    for (int i = threadIdx.x; i < snb; i += 256) bhs[(size_t)i * NB + blk] = h[dnb + i];
}

__global__ __launch_bounds__(256) void hist_fused(
        const int* __restrict__ src0, const int* __restrict__ dst0, int E0,
        const int* __restrict__ src1, const int* __restrict__ dst1, int E1,
        int* __restrict__ bh) {
    extern __shared__ int h[];
    if (blockIdx.x < NB0)
        hist_body(src0, dst0, E0, SH_S0, NK_S0, SH_D0, NK_D0, NB0, blockIdx.x,
                  bh + BH_D0, bh + BH_S0, h);
    else
        hist_body(src1, dst1, E1, SH_S1, NK_S1, SH_D1, NK_D1, NB1, blockIdx.x - NB0,
                  bh + BH_D1, bh + BH_S1, h);
}

// ============ global exclusive scan over bh ============
#define SCAN_ITEMS 8
#define SCAN_TILE 2048

__global__ __launch_bounds__(256) void scan1_kernel(
        const int* __restrict__ in, int* __restrict__ out,
        int* __restrict__ sums, int n) {
    __shared__ int lds[256];
    const int tid = threadIdx.x;
    const int base = blockIdx.x * SCAN_TILE + tid * SCAN_ITEMS;
    int v[SCAN_ITEMS];
    int run = 0;
    #pragma unroll
    for (int i = 0; i < SCAN_ITEMS; ++i) {
        int t = (base + i < n) ? in[base + i] : 0;
        v[i] = run;
        run += t;
    }
    lds[tid] = run;
    __syncthreads();
    int incl = run;
    for (int off = 1; off < 256; off <<= 1) {
        int u = (tid >= off) ? lds[tid - off] : 0;
        __syncthreads();
        incl += u;
        lds[tid] = incl;
        __syncthreads();
    }
    if (tid == 255) sums[blockIdx.x] = incl;
    int excl = incl - run;
    #pragma unroll
    for (int i = 0; i < SCAN_ITEMS; ++i)
        if (base + i < n) out[base + i] = excl + v[i];
}

__global__ __launch_bounds__(256) void scan2_kernel(int* __restrict__ sums, int nb) {
    __shared__ int lds[256];
    const int tid = threadIdx.x;
    const int base = tid * 4;
    int v[4];
    int run = 0;
    #pragma unroll
    for (int i = 0; i < 4; ++i) {
        int t = (base + i < nb) ? sums[base + i] : 0;
        v[i] = run;
        run += t;
    }
    lds[tid] = run;
    __syncthreads();
    int incl = run;
    for (int off = 1; off < 256; off <<= 1) {
        int u = (tid >= off) ? lds[tid - off] : 0;
        __syncthreads();
        incl += u;
        lds[tid] = incl;
        __syncthreads();
    }
    int excl = incl - run;
    #pragma unroll
    for (int i = 0; i < 4; ++i)
        if (base + i < nb) sums[base + i] = excl + v[i];
}

__global__ void scan3_kernel(int* __restrict__ out, const int* __restrict__ sums, int n) {
    int i = blockIdx.x * blockDim.x + threadIdx.x;
    if (i < n) out[i] += sums[i / SCAN_TILE];
}

// ============ pass 2: scatter to bucket-major u32 staging ============
// dst-keyed entry: (d_local << ksh) | s ; src-keyed entry: s
__device__ __forceinline__ void scat_body(
        const int* __restrict__ src, const int* __restrict__ dst, int n,
        int sshift, int snb, int dshift, int dnb, int NB, int blk, int ksh,
        const int* __restrict__ bhd, const int* __restrict__ bhs,
        uint32_t* __restrict__ stg, int* cur) {
    for (int i = threadIdx.x; i < dnb; i += 256) cur[i] = bhd[(size_t)i * NB + blk];
    for (int i = threadIdx.x; i < snb; i += 256) cur[dnb + i] = bhs[(size_t)i * NB + blk];
    __syncthreads();
    const int per = (n + NB - 1) / NB;
    const int b = blk * per;
    const int e = min(b + per, n);
    const int dmask = (1 << dshift) - 1;
    for (int i = b + threadIdx.x; i < e; i += 256) {
        int s = src[i], d = dst[i];
        int pd = atomicAdd(&cur[d >> dshift], 1);
        stg[pd] = ((uint32_t)(d & dmask) << ksh) | (uint32_t)s;
        int ps = atomicAdd(&cur[dnb + (s >> sshift)], 1);
        stg[ps] = (uint32_t)s;
    }
}

__global__ __launch_bounds__(256) void scat_fused(
        const int* __restrict__ src0, const int* __restrict__ dst0, int E0,
        const int* __restrict__ src1, const int* __restrict__ dst1, int E1,
        const int* __restrict__ bh, uint32_t* __restrict__ stg) {
    extern __shared__ int cur[];
    if (blockIdx.x < NB0)
        scat_body(src0, dst0, E0, SH_S0, NK_S0, SH_D0, NK_D0, NB0, blockIdx.x, 19,
                  bh + BH_D0, bh + BH_S0, stg, cur);
    else
        scat_body(src1, dst1, E1, SH_S1, NK_S1, SH_D1, NK_D1, NB1, blockIdx.x - NB0, 17,
                  bh + BH_D1, bh + BH_S1, stg, cur);
}

// ============ pass 3: per-bucket fine CSR / degree (fused 4 roles) ============
__device__ __forceinline__ void fine_csr_body(
        const uint32_t* __restrict__ stg, const int* __restrict__ bht,
        int NB, int shift, int ksh, int nbins, int total, int rel, int nbkt, int k,
        int* __restrict__ off, int* __restrict__ esrc, int* fine, int* part) {
    const int fb = 1 << shift;
    const int base = bht[(size_t)k * NB];
    const int end = (k + 1 < nbkt) ? bht[(size_t)(k + 1) * NB] : total;
    const int gb = k << shift;
    const int t = threadIdx.x;
    const uint32_t mask = (1u << ksh) - 1;
    for (int i = t; i < fb; i += 256) fine[i] = 0;
    __syncthreads();
    for (int i = base + t; i < end; i += 256)
        atomicAdd(&fine[stg[i] >> ksh], 1);
    __syncthreads();
    int a0 = (2 * t < fb) ? fine[2 * t] : 0;
    int a1 = (2 * t + 1 < fb) ? fine[2 * t + 1] : 0;
    part[t] = a0 + a1;
    __syncthreads();
    int incl = part[t];
    for (int o = 1; o < 256; o <<= 1) {
        int u = (t >= o) ? part[t - o] : 0;
        __syncthreads();
        incl += u;
        part[t] = incl;
        __syncthreads();
    }
    int excl = incl - (a0 + a1);
    if (2 * t < fb) fine[2 * t] = excl;
    if (2 * t + 1 < fb) fine[2 * t + 1] = excl + a0;
    __syncthreads();
    const int rb = base - rel;
    for (int i = t; i < fb; i += 256) {
        int g = gb + i;
        if (g < nbins) off[g] = rb + fine[i];
    }
    if (k == nbkt - 1 && t == 0) off[nbins] = total - rel;
    __syncthreads();
    for (int i = base + t; i < end; i += 256) {
        uint32_t v = stg[i];
        int p = atomicAdd(&fine[v >> ksh], 1);
        esrc[rb + p] = (int)(v & mask);
    }
}

__device__ __forceinline__ void fine_deg_body(
        const uint32_t* __restrict__ stg, const int* __restrict__ bht,
        int NB, int shift, int nbins, int total, int nbkt, int k,
        float* __restrict__ csf, int* fine) {
    const int fb = 1 << shift;
    const int base = bht[(size_t)k * NB];
    const int end = (k + 1 < nbkt) ? bht[(size_t)(k + 1) * NB] : total;
    const int gb = k << shift;
    for (int i = threadIdx.x; i < fb; i += 256) fine[i] = 0;
    __syncthreads();
    for (int i = base + threadIdx.x; i < end; i += 256)
        atomicAdd(&fine[(int)stg[i] - gb], 1);
    __syncthreads();
    for (int i = threadIdx.x; i < fb; i += 256) {
        int g = gb + i;
        if (g < nbins) {
            int c = fine[i];
            csf[g] = c > 0 ? rsqrtf((float)c) : 0.f;
        }
    }
}

__global__ __launch_bounds__(256) void fine_fused(
        const uint32_t* __restrict__ stg, const int* __restrict__ bh,
        int E0, int E1,
        int* __restrict__ off0, int* __restrict__ esrc0,
        int* __restrict__ off1, int* __restrict__ esrc1,
        float* __restrict__ cs0, float* __restrict__ cs1) {
    __shared__ int fine[512];
    __shared__ int part[256];
    int kb = blockIdx.x;
    if (kb < NK_D0) {
        fine_csr_body(stg, bh + BH_D0, NB0, SH_D0, 19, N_DST0, E0, 0, NK_D0, kb,
                      off0, esrc0, fine, part);
        return;
    }
    kb -= NK_D0;
    if (kb < NK_S0) {
        fine_deg_body(stg, bh + BH_S0, NB0, SH_S0, N_SRC0, 2 * E0, NK_S0, kb,
                      cs0, fine);
        return;
    }
    kb -= NK_S0;
    if (kb < NK_D1) {
        fine_csr_body(stg, bh + BH_D1, NB1, SH_D1, 17, N_DST1, 2 * E0 + E1, 2 * E0, NK_D1, kb,
                      off1, esrc1, fine, part);
        return;
    }
    kb -= NK_D1;
    fine_deg_body(stg, bh + BH_S1, NB1, SH_S1, N_DST0, 2 * E0 + 2 * E1, NK_S1, kb,
                  cs1, fine);
}

// ---------------- prescale: xs = f16(x * cs0), [N_SRC0,128] ----------------
__global__ __launch_bounds__(256) void prescale_kernel(
        const float4* __restrict__ x4, const float* __restrict__ cs,
        uint2* __restrict__ xs) {
    int id = blockIdx.x * 256 + threadIdx.x;
    int row = id >> 5;   // 32 float4 per row
    float c = cs[row];
    float4 v = x4[id];
    uint2 o;
    o.x = __builtin_bit_cast(uint32_t, __floats2half2_rn(v.x * c, v.y * c));
    o.y = __builtin_bit_cast(uint32_t, __floats2half2_rn(v.z * c, v.w * c));
    xs[id] = o;
}

// ---------------- weight packs (fused) ----------------
__global__ __launch_bounds__(256) void packw_fused(
        const float* __restrict__ W0, const float* __restrict__ W1,
        unsigned short* __restrict__ W0p, unsigned short* __restrict__ W1p) {
    int blk = blockIdx.x;
    if (blk < 128) {
        int id = blk * 256 + threadIdx.x;
        int kk = id & 31, n2 = (id >> 5) & 255, kt = id >> 13;
        W0p[id] = f2bf(W0[(kt * 32 + kk) * 256 + n2]);
    } else {
        int id = (blk - 128) * 256 + threadIdx.x;
        int kk = id & 31, n2 = (id >> 5) & 63, kt = id >> 11;
        W1p[id] = f2bf(W1[(kt * 32 + kk) * 64 + n2]);
    }
}

// ---------------- layer-0 aggregation: 64 lanes/row, u32 f16 gather, pk_add ----
__global__ __launch_bounds__(256) void agg0_kernel(
        const uint32_t* __restrict__ xs, const int* __restrict__ esrc,
        const int* __restrict__ off, uint32_t* __restrict__ aggb) {
    const int row = blockIdx.x * 4 + (threadIdx.x >> 6);
    const int t = threadIdx.x & 63;
    const int b = off[row], e = off[row + 1];
    const __half2 z = __builtin_bit_cast(__half2, 0u);
    __half2 a0 = z, a1 = z, a2 = z, a3 = z, a4 = z, a5 = z, a6 = z, a7 = z;
    int i = b;
    for (; i + 7 < e; i += 8) {
        int s0 = esrc[i],     s1 = esrc[i + 1], s2 = esrc[i + 2], s3 = esrc[i + 3];
        int s4 = esrc[i + 4], s5 = esrc[i + 5], s6 = esrc[i + 6], s7 = esrc[i + 7];
        a0 = __hadd2(a0, u2h2(xs[(size_t)s0 * 64 + t]));
        a1 = __hadd2(a1, u2h2(xs[(size_t)s1 * 64 + t]));
        a2 = __hadd2(a2, u2h2(xs[(size_t)s2 * 64 + t]));
        a3 = __hadd2(a3, u2h2(xs[(size_t)s3 * 64 + t]));
        a4 = __hadd2(a4, u2h2(xs[(size_t)s4 * 64 + t]));
        a5 = __hadd2(a5, u2h2(xs[(size_t)s5 * 64 + t]));
        a6 = __hadd2(a6, u2h2(xs[(size_t)s6 * 64 + t]));
        a7 = __hadd2(a7, u2h2(xs[(size_t)s7 * 64 + t]));
    }
    for (; i < e; ++i)
        a0 = __hadd2(a0, u2h2(xs[(size_t)esrc[i] * 64 + t]));
    __half2 s = __hadd2(__hadd2(__hadd2(a0, a1), __hadd2(a2, a3)),
                        __hadd2(__hadd2(a4, a5), __hadd2(a6, a7)));
    float cd = (e > b) ? rsqrtf((float)(e - b)) : 0.f;
    aggb[(size_t)row * 64 + t] = packbf2(__low2float(s) * cd, __high2float(s) * cd);
}

// ---------------- fused GEMM: h = relu(agg@W0+b0) in LDS; y = (h@W1)*cs1 ----
// block = 4 waves, 32 rows. Phase A: wave w -> h[32][w*64..+64]. Phase B: wave w -> y[32][w*16..+16].
__global__ __launch_bounds__(256) void gemm01_mfma(
        const short* __restrict__ A,            // aggb [N_DST0][128] bf16
        const short* __restrict__ B0p,          // [4][256][32] bf16
        const float* __restrict__ bias0,        // [256]
        const short* __restrict__ B1p,          // [8][64][32] bf16
        const float* __restrict__ cs1,          // [N_DST0]
        __half* __restrict__ Y) {               // [N_DST0][64] f16
    __shared__ short hs[32][272];               // +16 bf16 pad: 4-way max on phase-B reads
    const int w = threadIdx.x >> 6;
    const int l = threadIdx.x & 63;
    const int rbase = blockIdx.x * 32;
    const int lr = l & 15;
    const int lk = (l >> 4) * 8;
    const int orow0 = (l >> 4) * 4;

    // ---- phase A: h tile ----
    {
        const int cbase = w * 64;
        f32x4 acc[2][4] = {};
        #pragma unroll
        for (int kt = 0; kt < 4; ++kt) {
            short8 a[2], b[4];
            #pragma unroll
            for (int rt = 0; rt < 2; ++rt)
                a[rt] = *(const short8*)(A + (size_t)(rbase + rt * 16 + lr) * 128 + kt * 32 + lk);
            #pragma unroll
            for (int ct = 0; ct < 4; ++ct)
                b[ct] = *(const short8*)(B0p + (size_t)(kt * 256 + cbase + ct * 16 + lr) * 32 + lk);
            #pragma unroll
            for (int rt = 0; rt < 2; ++rt)
                #pragma unroll
                for (int ct = 0; ct < 4; ++ct)
                    acc[rt][ct] = __builtin_amdgcn_mfma_f32_16x16x32_bf16(a[rt], b[ct], acc[rt][ct], 0, 0, 0);
        }
        #pragma unroll
        for (int rt = 0; rt < 2; ++rt) {
            #pragma unroll
            for (int ct = 0; ct < 4; ++ct) {
                int col = cbase + ct * 16 + lr;
                float bv = bias0[col];
                #pragma unroll
                for (int j = 0; j < 4; ++j)
                    hs[rt * 16 + orow0 + j][col] = (short)f2bf(fmaxf(acc[rt][ct][j] + bv, 0.f));
            }
        }
    }
    __syncthreads();

    // ---- phase B: y tile, wave w covers cols [w*16, w*16+16), K = 256 ----
    {
        f32x4 acc2[2] = {};
        #pragma unroll
        for (int kt = 0; kt < 8; ++kt) {
            short8 b1 = *(const short8*)(B1p + (size_t)(kt * 64 + w * 16 + lr) * 32 + lk);
            #pragma unroll
            for (int rt = 0; rt < 2; ++rt) {
                short8 av = *(const short8*)(&hs[rt * 16 + lr][kt * 32 + lk]);
                acc2[rt] = __builtin_amdgcn_mfma_f32_16x16x32_bf16(av, b1, acc2[rt], 0, 0, 0);
            }
        }
        #pragma unroll
        for (int rt = 0; rt < 2; ++rt) {
            #pragma unroll
            for (int j = 0; j < 4; ++j) {
                int row = rbase + rt * 16 + orow0 + j;
                float c = cs1[row];
                Y[(size_t)row * 64 + w * 16 + lr] = __float2half(acc2[rt][j] * c);
            }
        }
    }
}

// ---------------- layer-1 aggregation: 16 lanes/row, uint2 f16 gather ------
__global__ __launch_bounds__(256) void agg1_kernel(
        const uint2* __restrict__ y2, const int* __restrict__ esrc,
        const int* __restrict__ off, const float* __restrict__ bias,
        float* __restrict__ out, int nrows) {
    int row = blockIdx.x * 16 + (threadIdx.x >> 4);
    int t = threadIdx.x & 15;
    if (row >= nrows) return;
    int b = off[row], e = off[row + 1];
    const __half2 z = __builtin_bit_cast(__half2, 0u);
    __half2 aA0 = z, aA1 = z, aB0 = z, aB1 = z;
    int i = b;
    for (; i + 8 <= e; i += 8) {
        #pragma unroll
        for (int k = 0; k < 8; k += 2) {
            int s0 = esrc[i + k], s1 = esrc[i + k + 1];
            uint2 v0 = y2[(size_t)s0 * 16 + t];
            uint2 v1 = y2[(size_t)s1 * 16 + t];
            aA0 = __hadd2(aA0, u2h2(v0.x));
            aA1 = __hadd2(aA1, u2h2(v0.y));
            aB0 = __hadd2(aB0, u2h2(v1.x));
            aB1 = __hadd2(aB1, u2h2(v1.y));
        }
    }
    for (; i < e; ++i) {
        uint2 v = y2[(size_t)esrc[i] * 16 + t];
        aA0 = __hadd2(aA0, u2h2(v.x));
        aA1 = __hadd2(aA1, u2h2(v.y));
    }
    float cd = (e > b) ? rsqrtf((float)(e - b)) : 0.f;
    __half2 s0 = __hadd2(aA0, aB0), s1 = __hadd2(aA1, aB1);
    float4 bv = *(const float4*)(bias + t * 4);
    float4 o;
    o.x = fmaxf(__low2float(s0) * cd + bv.x, 0.f);
    o.y = fmaxf(__high2float(s0) * cd + bv.y, 0.f);
    o.z = fmaxf(__low2float(s1) * cd + bv.z, 0.f);
    o.w = fmaxf(__high2float(s1) * cd + bv.w, 0.f);
    *(float4*)(out + (size_t)row * 64 + t * 4) = o;
}

extern "C" void kernel_launch(void* const* d_in, const int* in_sizes, int n_in,
                              void* d_out, int out_size, void* d_ws, size_t ws_size,
                              hipStream_t stream) {
    const float* x    = (const float*)d_in[0];
    const int*   src0 = (const int*)d_in[1];
    const int*   dst0 = (const int*)d_in[2];
    const int*   src1 = (const int*)d_in[3];
    const int*   dst1 = (const int*)d_in[4];
    const float* W0   = (const float*)d_in[5];
    const float* b0   = (const float*)d_in[6];
    const float* W1   = (const float*)d_in[7];
    const float* b1   = (const float*)d_in[8];
    float* out = (float*)d_out;

    const int E0 = in_sizes[1];
    const int E1 = in_sizes[3];

    char* p = (char*)d_ws;
    auto alloc = [&](size_t bytes) {
        char* r = p;
        p += (bytes + 511) & ~(size_t)511;
        return r;
    };
    int*   bh    = (int*)alloc((size_t)BH_TOT * 4);
    int*   sums  = (int*)alloc(1024 * 4);
    int*   off0  = (int*)alloc((size_t)(N_DST0 + 1) * 4);
    int*   off1  = (int*)alloc((size_t)(N_DST1 + 1) * 4);
    float* cs0   = (float*)alloc((size_t)N_SRC0 * 4);
    float* cs1   = (float*)alloc((size_t)N_DST0 * 4);
    int*   esrc0 = (int*)alloc((size_t)E0 * 4);
    int*   esrc1 = (int*)alloc((size_t)E1 * 4);
    unsigned short* W0p = (unsigned short*)alloc((size_t)32768 * 2);
    unsigned short* W1p = (unsigned short*)alloc((size_t)16384 * 2);
    // big region: stg (u32[2E0+2E1] = 32MB, dead before prescale);
    // then xs (102.4MB) at offset 0 -- after agg0, xs dead and y1b (12.8MB) reuses offset 0;
    // aggb (25.6MB) lives at offset bigA throughout layer 0.
    size_t bigA = (size_t)N_SRC0 * 128 * 2;   // xs (f16), later y1b (f16)
    size_t bigB = (size_t)N_DST0 * 128 * 2;   // aggb (bf16)
    size_t bigStg = (size_t)(2 * E0 + 2 * E1) * 4;
    size_t bigSz = bigA + bigB;
    if (bigStg > bigSz) bigSz = bigStg;
    char* big = alloc(bigSz);

    uint32_t* stg  = (uint32_t*)big;
    uint2*    xs   = (uint2*)big;
    __half*   y1b  = (__half*)big;              // reuses xs region after agg0
    uint32_t* aggb = (uint32_t*)(big + bigA);

    // --- CSR build: hist -> scan -> scatter -> fine (no global atomics) ---
    hist_fused<<<NB0 + NB1, 256, (NK_D0 + NK_S0) * 4, stream>>>(
        src0, dst0, E0, src1, dst1, E1, bh);
    const int nsb = (BH_TOT + SCAN_TILE - 1) / SCAN_TILE;   // 526
    scan1_kernel<<<nsb, 256, 0, stream>>>(bh, bh, sums, BH_TOT);
    scan2_kernel<<<1, 256, 0, stream>>>(sums, nsb);
    scan3_kernel<<<(BH_TOT + 255) / 256, 256, 0, stream>>>(bh, sums, BH_TOT);
    scat_fused<<<NB0 + NB1, 256, (NK_D0 + NK_S0) * 4, stream>>>(
        src0, dst0, E0, src1, dst1, E1, bh, stg);
    fine_fused<<<NK_D0 + NK_S0 + NK_D1 + NK_S1, 256, 0, stream>>>(
        stg, bh, E0, E1, off0, esrc0, off1, esrc1, cs0, cs1);

    // --- weight packs + prescale x -> f16 (stg fully consumed) ---
    packw_fused<<<192, 256, 0, stream>>>(W0, W1, W0p, W1p);
    prescale_kernel<<<N_SRC0 * 32 / 256, 256, 0, stream>>>((const float4*)x, cs0, xs);

    // layer 0 aggregation
    agg0_kernel<<<N_DST0 / 4, 256, 0, stream>>>(
        (const uint32_t*)xs, esrc0, off0, aggb);

    // fused GEMM0 + GEMM-T (h tile stays in LDS; writes y1b into dead xs region)
    gemm01_mfma<<<N_DST0 / 32, 256, 0, stream>>>(
        (const short*)aggb, (const short*)W0p, b0, (const short*)W1p, cs1, y1b);

    // layer 1 aggregation
    agg1_kernel<<<(N_DST1 + 15) / 16, 256, 0, stream>>>(
        (const uint2*)y1b, esrc1, off1, b1, out, N_DST1);
}

// Round 8
// 388.884 us; speedup vs baseline: 22.1364x; 1.0225x over previous
//
#include <hip/hip_runtime.h>
#include <hip/hip_bf16.h>
#include <hip/hip_fp16.h>
#include <stdint.h>

#define N_SRC0 400000
#define N_DST0 100000
#define N_DST1 25000

// coarse-bucket geometry (node counts are fixed)
#define SH_D0 9
#define NK_D0 196      // ceil(100000/512)
#define SH_S0 9
#define NK_S0 782      // ceil(400000/512)
#define SH_D1 8
#define NK_D1 98       // ceil(25000/256)
#define SH_S1 9
#define NK_S1 196      // ceil(100000/512)
#define NB0 1024
#define NB1 256

// bh concatenated layout offsets (scan order == staging order)
#define BH_D0 0
#define BH_S0 (NK_D0 * NB0)
#define BH_D1 (BH_S0 + NK_S0 * NB0)
#define BH_S1 (BH_D1 + NK_D1 * NB1)
#define BH_TOT (BH_S1 + NK_S1 * NB1)

typedef __attribute__((ext_vector_type(8))) short short8;
typedef __attribute__((ext_vector_type(4))) float f32x4;

__device__ __forceinline__ unsigned short f2bf(float f) {
    __hip_bfloat16 h = __float2bfloat16(f);
    union { __hip_bfloat16 h; unsigned short u; } c;
    c.h = h;
    return c.u;
}
__device__ __forceinline__ uint32_t packbf2(float a, float b) {
    return (uint32_t)f2bf(a) | ((uint32_t)f2bf(b) << 16);
}
__device__ __forceinline__ __half2 u2h2(uint32_t u) {
    return __builtin_bit_cast(__half2, u);
}

// ============ pass 1: per-block coarse histograms (src & dst fused) ============
__device__ __forceinline__ void hist_body(
        const int* __restrict__ src, const int* __restrict__ dst, int n,
        int sshift, int snb, int dshift, int dnb, int NB, int blk,
        int* __restrict__ bhd, int* __restrict__ bhs, int* h) {
    for (int i = threadIdx.x; i < dnb + snb; i += 256) h[i] = 0;
    __syncthreads();
    const int per = (n + NB - 1) / NB;
    const int b = blk * per;
    const int e = min(b + per, n);
    for (int i = b + threadIdx.x; i < e; i += 256) {
        atomicAdd(&h[dst[i] >> dshift], 1);
        atomicAdd(&h[dnb + (src[i] >> sshift)], 1);
    }
    __syncthreads();
    for (int i = threadIdx.x; i < dnb; i += 256) bhd[(size_t)i * NB + blk] = h[i];
    for (int i = threadIdx.x; i < snb; i += 256) bhs[(size_t)i * NB + blk] = h[dnb + i];
}

__global__ __launch_bounds__(256) void hist_fused(
        const int* __restrict__ src0, const int* __restrict__ dst0, int E0,
        const int* __restrict__ src1, const int* __restrict__ dst1, int E1,
        int* __restrict__ bh) {
    extern __shared__ int h[];
    if (blockIdx.x < NB0)
        hist_body(src0, dst0, E0, SH_S0, NK_S0, SH_D0, NK_D0, NB0, blockIdx.x,
                  bh + BH_D0, bh + BH_S0, h);
    else
        hist_body(src1, dst1, E1, SH_S1, NK_S1, SH_D1, NK_D1, NB1, blockIdx.x - NB0,
                  bh + BH_D1, bh + BH_S1, h);
}

// ============ global exclusive scan over bh ============
#define SCAN_ITEMS 8
#define SCAN_TILE 2048

__global__ __launch_bounds__(256) void scan1_kernel(
        const int* __restrict__ in, int* __restrict__ out,
        int* __restrict__ sums, int n) {
    __shared__ int lds[256];
    const int tid = threadIdx.x;
    const int base = blockIdx.x * SCAN_TILE + tid * SCAN_ITEMS;
    int v[SCAN_ITEMS];
    int run = 0;
    #pragma unroll
    for (int i = 0; i < SCAN_ITEMS; ++i) {
        int t = (base + i < n) ? in[base + i] : 0;
        v[i] = run;
        run += t;
    }
    lds[tid] = run;
    __syncthreads();
    int incl = run;
    for (int off = 1; off < 256; off <<= 1) {
        int u = (tid >= off) ? lds[tid - off] : 0;
        __syncthreads();
        incl += u;
        lds[tid] = incl;
        __syncthreads();
    }
    if (tid == 255) sums[blockIdx.x] = incl;
    int excl = incl - run;
    #pragma unroll
    for (int i = 0; i < SCAN_ITEMS; ++i)
        if (base + i < n) out[base + i] = excl + v[i];
}

__global__ __launch_bounds__(256) void scan2_kernel(int* __restrict__ sums, int nb) {
    __shared__ int lds[256];
    const int tid = threadIdx.x;
    const int base = tid * 4;
    int v[4];
    int run = 0;
    #pragma unroll
    for (int i = 0; i < 4; ++i) {
        int t = (base + i < nb) ? sums[base + i] : 0;
        v[i] = run;
        run += t;
    }
    lds[tid] = run;
    __syncthreads();
    int incl = run;
    for (int off = 1; off < 256; off <<= 1) {
        int u = (tid >= off) ? lds[tid - off] : 0;
        __syncthreads();
        incl += u;
        lds[tid] = incl;
        __syncthreads();
    }
    int excl = incl - run;
    #pragma unroll
    for (int i = 0; i < 4; ++i)
        if (base + i < nb) sums[base + i] = excl + v[i];
}

__global__ void scan3_kernel(int* __restrict__ out, const int* __restrict__ sums, int n) {
    int i = blockIdx.x * blockDim.x + threadIdx.x;
    if (i < n) out[i] += sums[i / SCAN_TILE];
}

// ============ pass 2: scatter to bucket-major u32 staging ============
// dst-keyed entry: (d_local << ksh) | s ; src-keyed entry: s
__device__ __forceinline__ void scat_body(
        const int* __restrict__ src, const int* __restrict__ dst, int n,
        int sshift, int snb, int dshift, int dnb, int NB, int blk, int ksh,
        const int* __restrict__ bhd, const int* __restrict__ bhs,
        uint32_t* __restrict__ stg, int* cur) {
    for (int i = threadIdx.x; i < dnb; i += 256) cur[i] = bhd[(size_t)i * NB + blk];
    for (int i = threadIdx.x; i < snb; i += 256) cur[dnb + i] = bhs[(size_t)i * NB + blk];
    __syncthreads();
    const int per = (n + NB - 1) / NB;
    const int b = blk * per;
    const int e = min(b + per, n);
    const int dmask = (1 << dshift) - 1;
    for (int i = b + threadIdx.x; i < e; i += 256) {
        int s = src[i], d = dst[i];
        int pd = atomicAdd(&cur[d >> dshift], 1);
        stg[pd] = ((uint32_t)(d & dmask) << ksh) | (uint32_t)s;
        int ps = atomicAdd(&cur[dnb + (s >> sshift)], 1);
        stg[ps] = (uint32_t)s;
    }
}

__global__ __launch_bounds__(256) void scat_fused(
        const int* __restrict__ src0, const int* __restrict__ dst0, int E0,
        const int* __restrict__ src1, const int* __restrict__ dst1, int E1,
        const int* __restrict__ bh, uint32_t* __restrict__ stg) {
    extern __shared__ int cur[];
    if (blockIdx.x < NB0)
        scat_body(src0, dst0, E0, SH_S0, NK_S0, SH_D0, NK_D0, NB0, blockIdx.x, 19,
                  bh + BH_D0, bh + BH_S0, stg, cur);
    else
        scat_body(src1, dst1, E1, SH_S1, NK_S1, SH_D1, NK_D1, NB1, blockIdx.x - NB0, 17,
                  bh + BH_D1, bh + BH_S1, stg, cur);
}

// ============ pass 3: per-bucket fine CSR / degree / weight-pack (fused) ============
__device__ __forceinline__ void fine_csr_body(
        const uint32_t* __restrict__ stg, const int* __restrict__ bht,
        int NB, int shift, int ksh, int nbins, int total, int rel, int nbkt, int k,
        int* __restrict__ off, int* __restrict__ esrc, int* fine, int* part) {
    const int fb = 1 << shift;
    const int base = bht[(size_t)k * NB];
    const int end = (k + 1 < nbkt) ? bht[(size_t)(k + 1) * NB] : total;
    const int gb = k << shift;
    const int t = threadIdx.x;
    const uint32_t mask = (1u << ksh) - 1;
    for (int i = t; i < fb; i += 256) fine[i] = 0;
    __syncthreads();
    for (int i = base + t; i < end; i += 256)
        atomicAdd(&fine[stg[i] >> ksh], 1);
    __syncthreads();
    int a0 = (2 * t < fb) ? fine[2 * t] : 0;
    int a1 = (2 * t + 1 < fb) ? fine[2 * t + 1] : 0;
    part[t] = a0 + a1;
    __syncthreads();
    int incl = part[t];
    for (int o = 1; o < 256; o <<= 1) {
        int u = (t >= o) ? part[t - o] : 0;
        __syncthreads();
        incl += u;
        part[t] = incl;
        __syncthreads();
    }
    int excl = incl - (a0 + a1);
    if (2 * t < fb) fine[2 * t] = excl;
    if (2 * t + 1 < fb) fine[2 * t + 1] = excl + a0;
    __syncthreads();
    const int rb = base - rel;
    for (int i = t; i < fb; i += 256) {
        int g = gb + i;
        if (g < nbins) off[g] = rb + fine[i];
    }
    if (k == nbkt - 1 && t == 0) off[nbins] = total - rel;
    __syncthreads();
    for (int i = base + t; i < end; i += 256) {
        uint32_t v = stg[i];
        int p = atomicAdd(&fine[v >> ksh], 1);
        esrc[rb + p] = (int)(v & mask);
    }
}

__device__ __forceinline__ void fine_deg_body(
        const uint32_t* __restrict__ stg, const int* __restrict__ bht,
        int NB, int shift, int nbins, int total, int nbkt, int k,
        float* __restrict__ csf, int* fine) {
    const int fb = 1 << shift;
    const int base = bht[(size_t)k * NB];
    const int end = (k + 1 < nbkt) ? bht[(size_t)(k + 1) * NB] : total;
    const int gb = k << shift;
    for (int i = threadIdx.x; i < fb; i += 256) fine[i] = 0;
    __syncthreads();
    for (int i = base + threadIdx.x; i < end; i += 256)
        atomicAdd(&fine[(int)stg[i] - gb], 1);
    __syncthreads();
    for (int i = threadIdx.x; i < fb; i += 256) {
        int g = gb + i;
        if (g < nbins) {
            int c = fine[i];
            csf[g] = c > 0 ? rsqrtf((float)c) : 0.f;
        }
    }
}

__global__ __launch_bounds__(256) void fine_fused(
        const uint32_t* __restrict__ stg, const int* __restrict__ bh,
        int E0, int E1,
        int* __restrict__ off0, int* __restrict__ esrc0,
        int* __restrict__ off1, int* __restrict__ esrc1,
        float* __restrict__ cs0, float* __restrict__ cs1,
        const float* __restrict__ W0, const float* __restrict__ W1,
        unsigned short* __restrict__ W0p, unsigned short* __restrict__ W1p) {
    __shared__ int fine[512];
    __shared__ int part[256];
    int kb = blockIdx.x;
    if (kb < NK_D0) {
        fine_csr_body(stg, bh + BH_D0, NB0, SH_D0, 19, N_DST0, E0, 0, NK_D0, kb,
                      off0, esrc0, fine, part);
        return;
    }
    kb -= NK_D0;
    if (kb < NK_S0) {
        fine_deg_body(stg, bh + BH_S0, NB0, SH_S0, N_SRC0, 2 * E0, NK_S0, kb,
                      cs0, fine);
        return;
    }
    kb -= NK_S0;
    if (kb < NK_D1) {
        fine_csr_body(stg, bh + BH_D1, NB1, SH_D1, 17, N_DST1, 2 * E0 + E1, 2 * E0, NK_D1, kb,
                      off1, esrc1, fine, part);
        return;
    }
    kb -= NK_D1;
    if (kb < NK_S1) {
        fine_deg_body(stg, bh + BH_S1, NB1, SH_S1, N_DST0, 2 * E0 + 2 * E1, NK_S1, kb,
                      cs1, fine);
        return;
    }
    kb -= NK_S1;
    // weight packs (independent of sort data)
    if (kb < 128) {
        int id = kb * 256 + threadIdx.x;
        int kk = id & 31, n2 = (id >> 5) & 255, kt = id >> 13;
        W0p[id] = f2bf(W0[(kt * 32 + kk) * 256 + n2]);
    } else {
        int id = (kb - 128) * 256 + threadIdx.x;
        int kk = id & 31, n2 = (id >> 5) & 63, kt = id >> 11;
        W1p[id] = f2bf(W1[(kt * 32 + kk) * 64 + n2]);
    }
}

// ---------------- prescale: xs = f16(x * cs0), [N_SRC0,128] ----------------
__global__ __launch_bounds__(256) void prescale_kernel(
        const float4* __restrict__ x4, const float* __restrict__ cs,
        uint2* __restrict__ xs) {
    int id = blockIdx.x * 256 + threadIdx.x;
    int row = id >> 5;   // 32 float4 per row
    float c = cs[row];
    float4 v = x4[id];
    uint2 o;
    o.x = __builtin_bit_cast(uint32_t, __floats2half2_rn(v.x * c, v.y * c));
    o.y = __builtin_bit_cast(uint32_t, __floats2half2_rn(v.z * c, v.w * c));
    xs[id] = o;
}

// ---------------- layer-0 aggregation: 64 lanes/row, u32 f16 gather, pk_add ----
// 32-bit offsets (xs table < 4GB) + deep unroll for MLP
__global__ __launch_bounds__(256) void agg0_kernel(
        const uint32_t* __restrict__ xs, const int* __restrict__ esrc,
        const int* __restrict__ off, uint32_t* __restrict__ aggb) {
    const int row = blockIdx.x * 4 + (threadIdx.x >> 6);
    const uint32_t t = threadIdx.x & 63;
    const int b = off[row], e = off[row + 1];
    const __half2 z = __builtin_bit_cast(__half2, 0u);
    __half2 a[16];
    #pragma unroll
    for (int k = 0; k < 16; ++k) a[k] = z;
    int i = b;
    for (; i + 15 < e; i += 16) {
        uint32_t idx[16];
        #pragma unroll
        for (int k = 0; k < 16; ++k)
            idx[k] = ((uint32_t)esrc[i + k] << 6) + t;
        #pragma unroll
        for (int k = 0; k < 16; ++k)
            a[k] = __hadd2(a[k], u2h2(xs[idx[k]]));
    }
    for (; i + 3 < e; i += 4) {
        #pragma unroll
        for (int k = 0; k < 4; ++k)
            a[k] = __hadd2(a[k], u2h2(xs[((uint32_t)esrc[i + k] << 6) + t]));
    }
    for (; i < e; ++i)
        a[0] = __hadd2(a[0], u2h2(xs[((uint32_t)esrc[i] << 6) + t]));
    #pragma unroll
    for (int k = 0; k < 8; ++k) a[k] = __hadd2(a[k], a[k + 8]);
    #pragma unroll
    for (int k = 0; k < 4; ++k) a[k] = __hadd2(a[k], a[k + 4]);
    __half2 s = __hadd2(__hadd2(a[0], a[1]), __hadd2(a[2], a[3]));
    float cd = (e > b) ? rsqrtf((float)(e - b)) : 0.f;
    aggb[(size_t)row * 64 + t] = packbf2(__low2float(s) * cd, __high2float(s) * cd);
}

// ---------------- fused GEMM: h = relu(agg@W0+b0) in LDS; y = (h@W1)*cs1 ----
// block = 4 waves, 32 rows. Phase A: wave w -> h[32][w*64..+64]. Phase B: wave w -> y[32][w*16..+16].
__global__ __launch_bounds__(256) void gemm01_mfma(
        const short* __restrict__ A,            // aggb [N_DST0][128] bf16
        const short* __restrict__ B0p,          // [4][256][32] bf16
        const float* __restrict__ bias0,        // [256]
        const short* __restrict__ B1p,          // [8][64][32] bf16
        const float* __restrict__ cs1,          // [N_DST0]
        __half* __restrict__ Y) {               // [N_DST0][64] f16
    __shared__ short hs[32][264];               // row stride 528B -> 4-dword bank step, 2-way (free)
    const int w = threadIdx.x >> 6;
    const int l = threadIdx.x & 63;
    const int rbase = blockIdx.x * 32;
    const int lr = l & 15;
    const int lk = (l >> 4) * 8;
    const int orow0 = (l >> 4) * 4;

    // ---- phase A: h tile ----
    {
        const int cbase = w * 64;
        f32x4 acc[2][4] = {};
        #pragma unroll
        for (int kt = 0; kt < 4; ++kt) {
            short8 a[2], b[4];
            #pragma unroll
            for (int rt = 0; rt < 2; ++rt)
                a[rt] = *(const short8*)(A + (size_t)(rbase + rt * 16 + lr) * 128 + kt * 32 + lk);
            #pragma unroll
            for (int ct = 0; ct < 4; ++ct)
                b[ct] = *(const short8*)(B0p + (size_t)(kt * 256 + cbase + ct * 16 + lr) * 32 + lk);
            #pragma unroll
            for (int rt = 0; rt < 2; ++rt)
                #pragma unroll
                for (int ct = 0; ct < 4; ++ct)
                    acc[rt][ct] = __builtin_amdgcn_mfma_f32_16x16x32_bf16(a[rt], b[ct], acc[rt][ct], 0, 0, 0);
        }
        #pragma unroll
        for (int rt = 0; rt < 2; ++rt) {
            #pragma unroll
            for (int ct = 0; ct < 4; ++ct) {
                int col = cbase + ct * 16 + lr;
                float bv = bias0[col];
                #pragma unroll
                for (int j = 0; j < 4; ++j)
                    hs[rt * 16 + orow0 + j][col] = (short)f2bf(fmaxf(acc[rt][ct][j] + bv, 0.f));
            }
        }
    }
    __syncthreads();

    // ---- phase B: y tile, wave w covers cols [w*16, w*16+16), K = 256 ----
    {
        f32x4 acc2[2] = {};
        #pragma unroll
        for (int kt = 0; kt < 8; ++kt) {
            short8 b1 = *(const short8*)(B1p + (size_t)(kt * 64 + w * 16 + lr) * 32 + lk);
            #pragma unroll
            for (int rt = 0; rt < 2; ++rt) {
                short8 av = *(const short8*)(&hs[rt * 16 + lr][kt * 32 + lk]);
                acc2[rt] = __builtin_amdgcn_mfma_f32_16x16x32_bf16(av, b1, acc2[rt], 0, 0, 0);
            }
        }
        #pragma unroll
        for (int rt = 0; rt < 2; ++rt) {
            #pragma unroll
            for (int j = 0; j < 4; ++j) {
                int row = rbase + rt * 16 + orow0 + j;
                float c = cs1[row];
                Y[(size_t)row * 64 + w * 16 + lr] = __float2half(acc2[rt][j] * c);
            }
        }
    }
}

// ---------------- layer-1 aggregation: 16 lanes/row, uint2 f16 gather ------
__global__ __launch_bounds__(256) void agg1_kernel(
        const uint2* __restrict__ y2, const int* __restrict__ esrc,
        const int* __restrict__ off, const float* __restrict__ bias,
        float* __restrict__ out, int nrows) {
    int row = blockIdx.x * 16 + (threadIdx.x >> 4);
    int t = threadIdx.x & 15;
    if (row >= nrows) return;
    int b = off[row], e = off[row + 1];
    const __half2 z = __builtin_bit_cast(__half2, 0u);
    __half2 aA0 = z, aA1 = z, aB0 = z, aB1 = z;
    int i = b;
    for (; i + 8 <= e; i += 8) {
        #pragma unroll
        for (int k = 0; k < 8; k += 2) {
            int s0 = esrc[i + k], s1 = esrc[i + k + 1];
            uint2 v0 = y2[(size_t)s0 * 16 + t];
            uint2 v1 = y2[(size_t)s1 * 16 + t];
            aA0 = __hadd2(aA0, u2h2(v0.x));
            aA1 = __hadd2(aA1, u2h2(v0.y));
            aB0 = __hadd2(aB0, u2h2(v1.x));
            aB1 = __hadd2(aB1, u2h2(v1.y));
        }
    }
    for (; i < e; ++i) {
        uint2 v = y2[(size_t)esrc[i] * 16 + t];
        aA0 = __hadd2(aA0, u2h2(v.x));
        aA1 = __hadd2(aA1, u2h2(v.y));
    }
    float cd = (e > b) ? rsqrtf((float)(e - b)) : 0.f;
    __half2 s0 = __hadd2(aA0, aB0), s1 = __hadd2(aA1, aB1);
    float4 bv = *(const float4*)(bias + t * 4);
    float4 o;
    o.x = fmaxf(__low2float(s0) * cd + bv.x, 0.f);
    o.y = fmaxf(__high2float(s0) * cd + bv.y, 0.f);
    o.z = fmaxf(__low2float(s1) * cd + bv.z, 0.f);
    o.w = fmaxf(__high2float(s1) * cd + bv.w, 0.f);
    *(float4*)(out + (size_t)row * 64 + t * 4) = o;
}

extern "C" void kernel_launch(void* const* d_in, const int* in_sizes, int n_in,
                              void* d_out, int out_size, void* d_ws, size_t ws_size,
                              hipStream_t stream) {
    const float* x    = (const float*)d_in[0];
    const int*   src0 = (const int*)d_in[1];
    const int*   dst0 = (const int*)d_in[2];
    const int*   src1 = (const int*)d_in[3];
    const int*   dst1 = (const int*)d_in[4];
    const float* W0   = (const float*)d_in[5];
    const float* b0   = (const float*)d_in[6];
    const float* W1   = (const float*)d_in[7];
    const float* b1   = (const float*)d_in[8];
    float* out = (float*)d_out;

    const int E0 = in_sizes[1];
    const int E1 = in_sizes[3];

    char* p = (char*)d_ws;
    auto alloc = [&](size_t bytes) {
        char* r = p;
        p += (bytes + 511) & ~(size_t)511;
        return r;
    };
    int*   bh    = (int*)alloc((size_t)BH_TOT * 4);
    int*   sums  = (int*)alloc(1024 * 4);
    int*   off0  = (int*)alloc((size_t)(N_DST0 + 1) * 4);
    int*   off1  = (int*)alloc((size_t)(N_DST1 + 1) * 4);
    float* cs0   = (float*)alloc((size_t)N_SRC0 * 4);
    float* cs1   = (float*)alloc((size_t)N_DST0 * 4);
    int*   esrc0 = (int*)alloc((size_t)E0 * 4);
    int*   esrc1 = (int*)alloc((size_t)E1 * 4);
    unsigned short* W0p = (unsigned short*)alloc((size_t)32768 * 2);
    unsigned short* W1p = (unsigned short*)alloc((size_t)16384 * 2);
    // big region: stg (u32[2E0+2E1] = 32MB, dead before prescale);
    // then xs (102.4MB) at offset 0 -- after agg0, xs dead and y1b (12.8MB) reuses offset 0;
    // aggb (25.6MB) lives at offset bigA throughout layer 0.
    size_t bigA = (size_t)N_SRC0 * 128 * 2;   // xs (f16), later y1b (f16)
    size_t bigB = (size_t)N_DST0 * 128 * 2;   // aggb (bf16)
    size_t bigStg = (size_t)(2 * E0 + 2 * E1) * 4;
    size_t bigSz = bigA + bigB;
    if (bigStg > bigSz) bigSz = bigStg;
    char* big = alloc(bigSz);

    uint32_t* stg  = (uint32_t*)big;
    uint2*    xs   = (uint2*)big;
    __half*   y1b  = (__half*)big;              // reuses xs region after agg0
    uint32_t* aggb = (uint32_t*)(big + bigA);

    // --- CSR build: hist -> scan -> scatter -> fine(+packw) (no global atomics) ---
    hist_fused<<<NB0 + NB1, 256, (NK_D0 + NK_S0) * 4, stream>>>(
        src0, dst0, E0, src1, dst1, E1, bh);
    const int nsb = (BH_TOT + SCAN_TILE - 1) / SCAN_TILE;   // 526
    scan1_kernel<<<nsb, 256, 0, stream>>>(bh, bh, sums, BH_TOT);
    scan2_kernel<<<1, 256, 0, stream>>>(sums, nsb);
    scan3_kernel<<<(BH_TOT + 255) / 256, 256, 0, stream>>>(bh, sums, BH_TOT);
    scat_fused<<<NB0 + NB1, 256, (NK_D0 + NK_S0) * 4, stream>>>(
        src0, dst0, E0, src1, dst1, E1, bh, stg);
    fine_fused<<<NK_D0 + NK_S0 + NK_D1 + NK_S1 + 192, 256, 0, stream>>>(
        stg, bh, E0, E1, off0, esrc0, off1, esrc1, cs0, cs1, W0, W1, W0p, W1p);

    // --- prescale x -> f16 (stg fully consumed) ---
    prescale_kernel<<<N_SRC0 * 32 / 256, 256, 0, stream>>>((const float4*)x, cs0, xs);

    // layer 0 aggregation
    agg0_kernel<<<N_DST0 / 4, 256, 0, stream>>>(
        (const uint32_t*)xs, esrc0, off0, aggb);

    // fused GEMM0 + GEMM-T (h tile stays in LDS; writes y1b into dead xs region)
    gemm01_mfma<<<N_DST0 / 32, 256, 0, stream>>>(
        (const short*)aggb, (const short*)W0p, b0, (const short*)W1p, cs1, y1b);

    // layer 1 aggregation
    agg1_kernel<<<(N_DST1 + 15) / 16, 256, 0, stream>>>(
        (const uint2*)y1b, esrc1, off1, b1, out, N_DST1);
}

// Round 9
// 381.373 us; speedup vs baseline: 22.5724x; 1.0197x over previous
//
#include <hip/hip_runtime.h>
#include <hip/hip_bf16.h>
#include <hip/hip_fp16.h>
#include <stdint.h>

#define N_SRC0 400000
#define N_DST0 100000
#define N_DST1 25000

// coarse-bucket geometry (node counts are fixed)
#define SH_D0 9
#define NK_D0 196      // ceil(100000/512)
#define SH_S0 9
#define NK_S0 782      // ceil(400000/512)
#define SH_D1 8
#define NK_D1 98       // ceil(25000/256)
#define SH_S1 9
#define NK_S1 196      // ceil(100000/512)
#define NB0 512
#define NB1 128

// bh concatenated layout offsets (element indices; scan order == staging order)
#define BH_D0 0
#define BH_S0 (NK_D0 * NB0)                    // 100352
#define BH_D1 (BH_S0 + NK_S0 * NB0)            // 500736
#define BH_S1 (BH_D1 + NK_D1 * NB1)            // 513280
#define BH_TOT (BH_S1 + NK_S1 * NB1)           // 538368

typedef __attribute__((ext_vector_type(8))) short short8;
typedef __attribute__((ext_vector_type(4))) float f32x4;

__device__ __forceinline__ unsigned short f2bf(float f) {
    __hip_bfloat16 h = __float2bfloat16(f);
    union { __hip_bfloat16 h; unsigned short u; } c;
    c.h = h;
    return c.u;
}
__device__ __forceinline__ uint32_t packbf2(float a, float b) {
    return (uint32_t)f2bf(a) | ((uint32_t)f2bf(b) << 16);
}
__device__ __forceinline__ __half2 u2h2(uint32_t u) {
    return __builtin_bit_cast(__half2, u);
}

// ============ pass 1: per-block coarse histograms (src & dst fused) ============
__device__ __forceinline__ void hist_body(
        const int* __restrict__ src, const int* __restrict__ dst, int n,
        int sshift, int snb, int dshift, int dnb, int NB, int blk,
        int* __restrict__ bhd, int* __restrict__ bhs, int* h) {
    for (int i = threadIdx.x; i < dnb + snb; i += 256) h[i] = 0;
    __syncthreads();
    const int per = (n + NB - 1) / NB;
    const int b = blk * per;
    const int e = min(b + per, n);
    for (int i = b + threadIdx.x; i < e; i += 256) {
        atomicAdd(&h[dst[i] >> dshift], 1);
        atomicAdd(&h[dnb + (src[i] >> sshift)], 1);
    }
    __syncthreads();
    for (int i = threadIdx.x; i < dnb; i += 256) bhd[(size_t)i * NB + blk] = h[i];
    for (int i = threadIdx.x; i < snb; i += 256) bhs[(size_t)i * NB + blk] = h[dnb + i];
}

__global__ __launch_bounds__(256) void hist_fused(
        const int* __restrict__ src0, const int* __restrict__ dst0, int E0,
        const int* __restrict__ src1, const int* __restrict__ dst1, int E1,
        int* __restrict__ bh) {
    extern __shared__ int h[];
    if (blockIdx.x < NB0)
        hist_body(src0, dst0, E0, SH_S0, NK_S0, SH_D0, NK_D0, NB0, blockIdx.x,
                  bh + BH_D0, bh + BH_S0, h);
    else
        hist_body(src1, dst1, E1, SH_S1, NK_S1, SH_D1, NK_D1, NB1, blockIdx.x - NB0,
                  bh + BH_D1, bh + BH_S1, h);
}

// ============ global exclusive scan over bh (block-local; sums folded later) ====
#define SCAN_ITEMS 8
#define SCAN_TILE 2048   // == 256 * SCAN_ITEMS; sums index = elem >> 11

__global__ __launch_bounds__(256) void scan1_kernel(
        const int* __restrict__ in, int* __restrict__ out,
        int* __restrict__ sums, int n) {
    __shared__ int lds[256];
    const int tid = threadIdx.x;
    const int base = blockIdx.x * SCAN_TILE + tid * SCAN_ITEMS;
    int v[SCAN_ITEMS];
    int run = 0;
    #pragma unroll
    for (int i = 0; i < SCAN_ITEMS; ++i) {
        int t = (base + i < n) ? in[base + i] : 0;
        v[i] = run;
        run += t;
    }
    lds[tid] = run;
    __syncthreads();
    int incl = run;
    for (int off = 1; off < 256; off <<= 1) {
        int u = (tid >= off) ? lds[tid - off] : 0;
        __syncthreads();
        incl += u;
        lds[tid] = incl;
        __syncthreads();
    }
    if (tid == 255) sums[blockIdx.x] = incl;
    int excl = incl - run;
    #pragma unroll
    for (int i = 0; i < SCAN_ITEMS; ++i)
        if (base + i < n) out[base + i] = excl + v[i];
}

__global__ __launch_bounds__(256) void scan2_kernel(int* __restrict__ sums, int nb) {
    __shared__ int lds[256];
    const int tid = threadIdx.x;
    const int base = tid * 4;
    int v[4];
    int run = 0;
    #pragma unroll
    for (int i = 0; i < 4; ++i) {
        int t = (base + i < nb) ? sums[base + i] : 0;
        v[i] = run;
        run += t;
    }
    lds[tid] = run;
    __syncthreads();
    int incl = run;
    for (int off = 1; off < 256; off <<= 1) {
        int u = (tid >= off) ? lds[tid - off] : 0;
        __syncthreads();
        incl += u;
        lds[tid] = incl;
        __syncthreads();
    }
    int excl = incl - run;
    #pragma unroll
    for (int i = 0; i < 4; ++i)
        if (base + i < nb) sums[base + i] = excl + v[i];
}

// ============ pass 2: scatter to bucket-major staging ============
// dst-keyed table (u32): (d_local << ksh) | s ; src-keyed table (u16): s & smask.
// cursors = bh[..] + sums[gidx>>11] - Ttable  (table-relative)
__device__ __forceinline__ void scat_body(
        const int* __restrict__ src, const int* __restrict__ dst, int n,
        int sshift, int snb, int dshift, int dnb, int NB, int blk, int ksh,
        const int* __restrict__ bhd, const int* __restrict__ bhs,
        const int* __restrict__ sums, int goffd, int goffs, int Td, int Ts,
        uint32_t* __restrict__ stg_d, unsigned short* __restrict__ stg_s, int* cur) {
    for (int i = threadIdx.x; i < dnb; i += 256) {
        int gi = goffd + i * NB + blk;
        cur[i] = bhd[(size_t)i * NB + blk] + sums[gi >> 11] - Td;
    }
    for (int i = threadIdx.x; i < snb; i += 256) {
        int gi = goffs + i * NB + blk;
        cur[dnb + i] = bhs[(size_t)i * NB + blk] + sums[gi >> 11] - Ts;
    }
    __syncthreads();
    const int per = (n + NB - 1) / NB;
    const int b = blk * per;
    const int e = min(b + per, n);
    const int dmask = (1 << dshift) - 1;
    const int smask = (1 << sshift) - 1;
    for (int i = b + threadIdx.x; i < e; i += 256) {
        int s = src[i], d = dst[i];
        int pd = atomicAdd(&cur[d >> dshift], 1);
        stg_d[pd] = ((uint32_t)(d & dmask) << ksh) | (uint32_t)s;
        int ps = atomicAdd(&cur[dnb + (s >> sshift)], 1);
        stg_s[ps] = (unsigned short)(s & smask);
    }
}

__global__ __launch_bounds__(256) void scat_fused(
        const int* __restrict__ src0, const int* __restrict__ dst0, int E0,
        const int* __restrict__ src1, const int* __restrict__ dst1, int E1,
        const int* __restrict__ bh, const int* __restrict__ sums,
        uint32_t* __restrict__ stgd0, unsigned short* __restrict__ stgs0,
        uint32_t* __restrict__ stgd1, unsigned short* __restrict__ stgs1) {
    extern __shared__ int cur[];
    if (blockIdx.x < NB0)
        scat_body(src0, dst0, E0, SH_S0, NK_S0, SH_D0, NK_D0, NB0, blockIdx.x, 19,
                  bh + BH_D0, bh + BH_S0, sums, BH_D0, BH_S0, 0, E0,
                  stgd0, stgs0, cur);
    else
        scat_body(src1, dst1, E1, SH_S1, NK_S1, SH_D1, NK_D1, NB1, blockIdx.x - NB0, 17,
                  bh + BH_D1, bh + BH_S1, sums, BH_D1, BH_S1, 2 * E0, 2 * E0 + E1,
                  stgd1, stgs1, cur);
}

// ============ pass 3: per-bucket fine CSR / degree / weight-pack (fused) ============
// bases are table-relative: base = bh[k*NB] + sums[(goff+k*NB)>>11] - T
__device__ __forceinline__ int fold_base(const int* bht, const int* sums,
                                         int goff, int NB, int T, int k) {
    int gi = goff + k * NB;
    return bht[(size_t)k * NB] + sums[gi >> 11] - T;
}

__device__ __forceinline__ void fine_csr_body(
        const uint32_t* __restrict__ stg, const int* __restrict__ bht,
        const int* __restrict__ sums, int goff, int T,
        int NB, int shift, int ksh, int nbins, int total, int nbkt, int k,
        int* __restrict__ off, int* __restrict__ esrc, int* fine, int* part) {
    const int fb = 1 << shift;
    const int base = fold_base(bht, sums, goff, NB, T, k);
    const int end = (k + 1 < nbkt) ? fold_base(bht, sums, goff, NB, T, k + 1) : total;
    const int gb = k << shift;
    const int t = threadIdx.x;
    const uint32_t mask = (1u << ksh) - 1;
    for (int i = t; i < fb; i += 256) fine[i] = 0;
    __syncthreads();
    for (int i = base + t; i < end; i += 256)
        atomicAdd(&fine[stg[i] >> ksh], 1);
    __syncthreads();
    int a0 = (2 * t < fb) ? fine[2 * t] : 0;
    int a1 = (2 * t + 1 < fb) ? fine[2 * t + 1] : 0;
    part[t] = a0 + a1;
    __syncthreads();
    int incl = part[t];
    for (int o = 1; o < 256; o <<= 1) {
        int u = (t >= o) ? part[t - o] : 0;
        __syncthreads();
        incl += u;
        part[t] = incl;
        __syncthreads();
    }
    int excl = incl - (a0 + a1);
    if (2 * t < fb) fine[2 * t] = excl;
    if (2 * t + 1 < fb) fine[2 * t + 1] = excl + a0;
    __syncthreads();
    for (int i = t; i < fb; i += 256) {
        int g = gb + i;
        if (g < nbins) off[g] = base + fine[i];
    }
    if (k == nbkt - 1 && t == 0) off[nbins] = total;
    __syncthreads();
    for (int i = base + t; i < end; i += 256) {
        uint32_t v = stg[i];
        int p = atomicAdd(&fine[v >> ksh], 1);
        esrc[base + p] = (int)(v & mask);
    }
}

__device__ __forceinline__ void fine_deg_body(
        const unsigned short* __restrict__ stg, const int* __restrict__ bht,
        const int* __restrict__ sums, int goff, int T,
        int NB, int shift, int nbins, int total, int nbkt, int k,
        float* __restrict__ csf, int* fine) {
    const int fb = 1 << shift;
    const int base = fold_base(bht, sums, goff, NB, T, k);
    const int end = (k + 1 < nbkt) ? fold_base(bht, sums, goff, NB, T, k + 1) : total;
    const int gb = k << shift;
    for (int i = threadIdx.x; i < fb; i += 256) fine[i] = 0;
    __syncthreads();
    for (int i = base + threadIdx.x; i < end; i += 256)
        atomicAdd(&fine[stg[i]], 1);
    __syncthreads();
    for (int i = threadIdx.x; i < fb; i += 256) {
        int g = gb + i;
        if (g < nbins) {
            int c = fine[i];
            csf[g] = c > 0 ? rsqrtf((float)c) : 0.f;
        }
    }
}

__global__ __launch_bounds__(256) void fine_fused(
        const uint32_t* __restrict__ stgd0, const unsigned short* __restrict__ stgs0,
        const uint32_t* __restrict__ stgd1, const unsigned short* __restrict__ stgs1,
        const int* __restrict__ bh, const int* __restrict__ sums,
        int E0, int E1,
        int* __restrict__ off0, int* __restrict__ esrc0,
        int* __restrict__ off1, int* __restrict__ esrc1,
        float* __restrict__ cs0, float* __restrict__ cs1,
        const float* __restrict__ W0, const float* __restrict__ W1,
        unsigned short* __restrict__ W0p, unsigned short* __restrict__ W1p) {
    __shared__ int fine[512];
    __shared__ int part[256];
    int kb = blockIdx.x;
    if (kb < NK_D0) {
        fine_csr_body(stgd0, bh + BH_D0, sums, BH_D0, 0,
                      NB0, SH_D0, 19, N_DST0, E0, NK_D0, kb, off0, esrc0, fine, part);
        return;
    }
    kb -= NK_D0;
    if (kb < NK_S0) {
        fine_deg_body(stgs0, bh + BH_S0, sums, BH_S0, E0,
                      NB0, SH_S0, N_SRC0, E0, NK_S0, kb, cs0, fine);
        return;
    }
    kb -= NK_S0;
    if (kb < NK_D1) {
        fine_csr_body(stgd1, bh + BH_D1, sums, BH_D1, 2 * E0,
                      NB1, SH_D1, 17, N_DST1, E1, NK_D1, kb, off1, esrc1, fine, part);
        return;
    }
    kb -= NK_D1;
    if (kb < NK_S1) {
        fine_deg_body(stgs1, bh + BH_S1, sums, BH_S1, 2 * E0 + E1,
                      NB1, SH_S1, N_DST0, E1, NK_S1, kb, cs1, fine);
        return;
    }
    kb -= NK_S1;
    // weight packs (independent of sort data)
    if (kb < 128) {
        int id = kb * 256 + threadIdx.x;
        int kk = id & 31, n2 = (id >> 5) & 255, kt = id >> 13;
        W0p[id] = f2bf(W0[(kt * 32 + kk) * 256 + n2]);
    } else {
        int id = (kb - 128) * 256 + threadIdx.x;
        int kk = id & 31, n2 = (id >> 5) & 63, kt = id >> 11;
        W1p[id] = f2bf(W1[(kt * 32 + kk) * 64 + n2]);
    }
}

// ---------------- prescale: xs = f16(x * cs0), [N_SRC0,128] ----------------
__global__ __launch_bounds__(256) void prescale_kernel(
        const float4* __restrict__ x4, const float* __restrict__ cs,
        uint2* __restrict__ xs) {
    int id = blockIdx.x * 256 + threadIdx.x;
    int row = id >> 5;   // 32 float4 per row
    float c = cs[row];
    float4 v = x4[id];
    uint2 o;
    o.x = __builtin_bit_cast(uint32_t, __floats2half2_rn(v.x * c, v.y * c));
    o.y = __builtin_bit_cast(uint32_t, __floats2half2_rn(v.z * c, v.w * c));
    xs[id] = o;
}

// ---------------- layer-0 aggregation: 64 lanes/row, u32 f16 gather, pk_add ----
__global__ __launch_bounds__(256) void agg0_kernel(
        const uint32_t* __restrict__ xs, const int* __restrict__ esrc,
        const int* __restrict__ off, uint32_t* __restrict__ aggb) {
    const int row = blockIdx.x * 4 + (threadIdx.x >> 6);
    const uint32_t t = threadIdx.x & 63;
    const int b = off[row], e = off[row + 1];
    const __half2 z = __builtin_bit_cast(__half2, 0u);
    __half2 a[16];
    #pragma unroll
    for (int k = 0; k < 16; ++k) a[k] = z;
    int i = b;
    for (; i + 15 < e; i += 16) {
        uint32_t idx[16];
        #pragma unroll
        for (int k = 0; k < 16; ++k)
            idx[k] = ((uint32_t)esrc[i + k] << 6) + t;
        #pragma unroll
        for (int k = 0; k < 16; ++k)
            a[k] = __hadd2(a[k], u2h2(xs[idx[k]]));
    }
    for (; i + 3 < e; i += 4) {
        #pragma unroll
        for (int k = 0; k < 4; ++k)
            a[k] = __hadd2(a[k], u2h2(xs[((uint32_t)esrc[i + k] << 6) + t]));
    }
    for (; i < e; ++i)
        a[0] = __hadd2(a[0], u2h2(xs[((uint32_t)esrc[i] << 6) + t]));
    #pragma unroll
    for (int k = 0; k < 8; ++k) a[k] = __hadd2(a[k], a[k + 8]);
    #pragma unroll
    for (int k = 0; k < 4; ++k) a[k] = __hadd2(a[k], a[k + 4]);
    __half2 s = __hadd2(__hadd2(a[0], a[1]), __hadd2(a[2], a[3]));
    float cd = (e > b) ? rsqrtf((float)(e - b)) : 0.f;
    aggb[(size_t)row * 64 + t] = packbf2(__low2float(s) * cd, __high2float(s) * cd);
}

// ---------------- fused GEMM: h = relu(agg@W0+b0) in LDS; y = (h@W1)*cs1 ----
__global__ __launch_bounds__(256) void gemm01_mfma(
        const short* __restrict__ A,            // aggb [N_DST0][128] bf16
        const short* __restrict__ B0p,          // [4][256][32] bf16
        const float* __restrict__ bias0,        // [256]
        const short* __restrict__ B1p,          // [8][64][32] bf16
        const float* __restrict__ cs1,          // [N_DST0]
        __half* __restrict__ Y) {               // [N_DST0][64] f16
    __shared__ short hs[32][264];               // row stride 528B: 2-way bank alias (free)
    const int w = threadIdx.x >> 6;
    const int l = threadIdx.x & 63;
    const int rbase = blockIdx.x * 32;
    const int lr = l & 15;
    const int lk = (l >> 4) * 8;
    const int orow0 = (l >> 4) * 4;

    // ---- phase A: h tile ----
    {
        const int cbase = w * 64;
        f32x4 acc[2][4] = {};
        #pragma unroll
        for (int kt = 0; kt < 4; ++kt) {
            short8 a[2], b[4];
            #pragma unroll
            for (int rt = 0; rt < 2; ++rt)
                a[rt] = *(const short8*)(A + (size_t)(rbase + rt * 16 + lr) * 128 + kt * 32 + lk);
            #pragma unroll
            for (int ct = 0; ct < 4; ++ct)
                b[ct] = *(const short8*)(B0p + (size_t)(kt * 256 + cbase + ct * 16 + lr) * 32 + lk);
            #pragma unroll
            for (int rt = 0; rt < 2; ++rt)
                #pragma unroll
                for (int ct = 0; ct < 4; ++ct)
                    acc[rt][ct] = __builtin_amdgcn_mfma_f32_16x16x32_bf16(a[rt], b[ct], acc[rt][ct], 0, 0, 0);
        }
        #pragma unroll
        for (int rt = 0; rt < 2; ++rt) {
            #pragma unroll
            for (int ct = 0; ct < 4; ++ct) {
                int col = cbase + ct * 16 + lr;
                float bv = bias0[col];
                #pragma unroll
                for (int j = 0; j < 4; ++j)
                    hs[rt * 16 + orow0 + j][col] = (short)f2bf(fmaxf(acc[rt][ct][j] + bv, 0.f));
            }
        }
    }
    __syncthreads();

    // ---- phase B: y tile, wave w covers cols [w*16, w*16+16), K = 256 ----
    {
        f32x4 acc2[2] = {};
        #pragma unroll
        for (int kt = 0; kt < 8; ++kt) {
            short8 b1 = *(const short8*)(B1p + (size_t)(kt * 64 + w * 16 + lr) * 32 + lk);
            #pragma unroll
            for (int rt = 0; rt < 2; ++rt) {
                short8 av = *(const short8*)(&hs[rt * 16 + lr][kt * 32 + lk]);
                acc2[rt] = __builtin_amdgcn_mfma_f32_16x16x32_bf16(av, b1, acc2[rt], 0, 0, 0);
            }
        }
        #pragma unroll
        for (int rt = 0; rt < 2; ++rt) {
            #pragma unroll
            for (int j = 0; j < 4; ++j) {
                int row = rbase + rt * 16 + orow0 + j;
                float c = cs1[row];
                Y[(size_t)row * 64 + w * 16 + lr] = __float2half(acc2[rt][j] * c);
            }
        }
    }
}

// ---------------- layer-1 aggregation: 16 lanes/row, uint2 f16 gather ------
__global__ __launch_bounds__(256) void agg1_kernel(
        const uint2* __restrict__ y2, const int* __restrict__ esrc,
        const int* __restrict__ off, const float* __restrict__ bias,
        float* __restrict__ out, int nrows) {
    int row = blockIdx.x * 16 + (threadIdx.x >> 4);
    int t = threadIdx.x & 15;
    if (row >= nrows) return;
    int b = off[row], e = off[row + 1];
    const __half2 z = __builtin_bit_cast(__half2, 0u);
    __half2 aA0 = z, aA1 = z, aB0 = z, aB1 = z;
    int i = b;
    for (; i + 8 <= e; i += 8) {
        #pragma unroll
        for (int k = 0; k < 8; k += 2) {
            int s0 = esrc[i + k], s1 = esrc[i + k + 1];
            uint2 v0 = y2[(size_t)s0 * 16 + t];
            uint2 v1 = y2[(size_t)s1 * 16 + t];
            aA0 = __hadd2(aA0, u2h2(v0.x));
            aA1 = __hadd2(aA1, u2h2(v0.y));
            aB0 = __hadd2(aB0, u2h2(v1.x));
            aB1 = __hadd2(aB1, u2h2(v1.y));
        }
    }
    for (; i < e; ++i) {
        uint2 v = y2[(size_t)esrc[i] * 16 + t];
        aA0 = __hadd2(aA0, u2h2(v.x));
        aA1 = __hadd2(aA1, u2h2(v.y));
    }
    float cd = (e > b) ? rsqrtf((float)(e - b)) : 0.f;
    __half2 s0 = __hadd2(aA0, aB0), s1 = __hadd2(aA1, aB1);
    float4 bv = *(const float4*)(bias + t * 4);
    float4 o;
    o.x = fmaxf(__low2float(s0) * cd + bv.x, 0.f);
    o.y = fmaxf(__high2float(s0) * cd + bv.y, 0.f);
    o.z = fmaxf(__low2float(s1) * cd + bv.z, 0.f);
    o.w = fmaxf(__high2float(s1) * cd + bv.w, 0.f);
    *(float4*)(out + (size_t)row * 64 + t * 4) = o;
}

extern "C" void kernel_launch(void* const* d_in, const int* in_sizes, int n_in,
                              void* d_out, int out_size, void* d_ws, size_t ws_size,
                              hipStream_t stream) {
    const float* x    = (const float*)d_in[0];
    const int*   src0 = (const int*)d_in[1];
    const int*   dst0 = (const int*)d_in[2];
    const int*   src1 = (const int*)d_in[3];
    const int*   dst1 = (const int*)d_in[4];
    const float* W0   = (const float*)d_in[5];
    const float* b0   = (const float*)d_in[6];
    const float* W1   = (const float*)d_in[7];
    const float* b1   = (const float*)d_in[8];
    float* out = (float*)d_out;

    const int E0 = in_sizes[1];
    const int E1 = in_sizes[3];

    char* p = (char*)d_ws;
    auto alloc = [&](size_t bytes) {
        char* r = p;
        p += (bytes + 511) & ~(size_t)511;
        return r;
    };
    int*   bh    = (int*)alloc((size_t)BH_TOT * 4);
    int*   sums  = (int*)alloc(1024 * 4);
    int*   off0  = (int*)alloc((size_t)(N_DST0 + 1) * 4);
    int*   off1  = (int*)alloc((size_t)(N_DST1 + 1) * 4);
    float* cs0   = (float*)alloc((size_t)N_SRC0 * 4);
    float* cs1   = (float*)alloc((size_t)N_DST0 * 4);
    int*   esrc0 = (int*)alloc((size_t)E0 * 4);
    int*   esrc1 = (int*)alloc((size_t)E1 * 4);
    unsigned short* W0p = (unsigned short*)alloc((size_t)32768 * 2);
    unsigned short* W1p = (unsigned short*)alloc((size_t)16384 * 2);
    // big region: staging tables (24MB, dead before prescale);
    // then xs (102.4MB) at offset 0 -- after agg0, y1b (12.8MB) reuses offset 0;
    // aggb (25.6MB) lives at offset bigA throughout layer 0.
    size_t bigA = (size_t)N_SRC0 * 128 * 2;   // xs (f16), later y1b (f16)
    size_t bigB = (size_t)N_DST0 * 128 * 2;   // aggb (bf16)
    size_t bigStg = (size_t)(E0 * 6 + E1 * 6 + 1024);
    size_t bigSz = bigA + bigB;
    if (bigStg > bigSz) bigSz = bigStg;
    char* big = alloc(bigSz);

    // staging layout (512B-aligned carve inside big)
    char* q = big;
    auto carve = [&](size_t bytes) {
        char* r = q;
        q += (bytes + 511) & ~(size_t)511;
        return r;
    };
    uint32_t*       stgd0 = (uint32_t*)carve((size_t)E0 * 4);
    unsigned short* stgs0 = (unsigned short*)carve((size_t)E0 * 2);
    uint32_t*       stgd1 = (uint32_t*)carve((size_t)E1 * 4);
    unsigned short* stgs1 = (unsigned short*)carve((size_t)E1 * 2);

    uint2*    xs   = (uint2*)big;
    __half*   y1b  = (__half*)big;              // reuses xs region after agg0
    uint32_t* aggb = (uint32_t*)(big + bigA);

    // --- CSR build: hist -> scan(2) -> scatter -> fine(+packw) ---
    hist_fused<<<NB0 + NB1, 256, (NK_D0 + NK_S0) * 4, stream>>>(
        src0, dst0, E0, src1, dst1, E1, bh);
    const int nsb = (BH_TOT + SCAN_TILE - 1) / SCAN_TILE;   // 263
    scan1_kernel<<<nsb, 256, 0, stream>>>(bh, bh, sums, BH_TOT);
    scan2_kernel<<<1, 256, 0, stream>>>(sums, nsb);
    scat_fused<<<NB0 + NB1, 256, (NK_D0 + NK_S0) * 4, stream>>>(
        src0, dst0, E0, src1, dst1, E1, bh, sums, stgd0, stgs0, stgd1, stgs1);
    fine_fused<<<NK_D0 + NK_S0 + NK_D1 + NK_S1 + 192, 256, 0, stream>>>(
        stgd0, stgs0, stgd1, stgs1, bh, sums, E0, E1,
        off0, esrc0, off1, esrc1, cs0, cs1, W0, W1, W0p, W1p);

    // --- prescale x -> f16 (staging fully consumed; big region repurposed) ---
    prescale_kernel<<<N_SRC0 * 32 / 256, 256, 0, stream>>>((const float4*)x, cs0, xs);

    // layer 0 aggregation
    agg0_kernel<<<N_DST0 / 4, 256, 0, stream>>>(
        (const uint32_t*)xs, esrc0, off0, aggb);

    // fused GEMM0 + GEMM-T (h tile stays in LDS; writes y1b into dead xs region)
    gemm01_mfma<<<N_DST0 / 32, 256, 0, stream>>>(
        (const short*)aggb, (const short*)W0p, b0, (const short*)W1p, cs1, y1b);

    // layer 1 aggregation
    agg1_kernel<<<(N_DST1 + 15) / 16, 256, 0, stream>>>(
        (const uint2*)y1b, esrc1, off1, b1, out, N_DST1);
}